// Round 1
// baseline (5150.503 us; speedup 1.0000x reference)
//
#include <hip/hip_runtime.h>

// RGCN: N=100k nodes, E=6.4M edges, R=90 relations, NB=3 block-diagonal.
// Layer dims: 3 -> 6 -> 3 -> 6, then global mean pool + log_softmax -> 6 outputs.

#define NREL 90
#define WSZ  540   // R * NB * in_b * out_b = 90*6 for every layer here

__device__ __forceinline__ float frelu(float v) { return v > 0.0f ? v : 0.0f; }

// ---------------- count edges per (dst, relation) ----------------
__global__ void count_kernel(const int* __restrict__ dst, const int* __restrict__ et,
                             int* __restrict__ cnt, int E) {
    int e = blockIdx.x * blockDim.x + threadIdx.x;
    if (e < E) atomicAdd(&cnt[dst[e] * NREL + et[e]], 1);
}

// ---------------- layer 1 edge: x[N,3] -> agg1[N,6], mean norm; cache rinv ----------------
__global__ void l1_edge(const int* __restrict__ src, const int* __restrict__ dst,
                        const int* __restrict__ et, const float* __restrict__ x,
                        const float* __restrict__ W, const int* __restrict__ cnt,
                        float* __restrict__ rinv, float* __restrict__ agg, int E) {
    __shared__ float w[WSZ];
    for (int i = threadIdx.x; i < WSZ; i += blockDim.x) w[i] = W[i];
    __syncthreads();
    int e = blockIdx.x * blockDim.x + threadIdx.x;
    if (e >= E) return;
    int s = src[e], d = dst[e], t = et[e];
    float r = 1.0f / (float)cnt[d * NREL + t];
    rinv[e] = r;
    float x0 = x[s * 3 + 0], x1 = x[s * 3 + 1], x2 = x[s * 3 + 2];
    const float* wt = &w[t * 6];
    float* a = &agg[d * 6];
    // msg[b*2+o] = x[b] * W[et, b, 0, o]
    unsafeAtomicAdd(&a[0], x0 * wt[0] * r);
    unsafeAtomicAdd(&a[1], x0 * wt[1] * r);
    unsafeAtomicAdd(&a[2], x1 * wt[2] * r);
    unsafeAtomicAdd(&a[3], x1 * wt[3] * r);
    unsafeAtomicAdd(&a[4], x2 * wt[4] * r);
    unsafeAtomicAdd(&a[5], x2 * wt[5] * r);
}

// ---------------- layer 1 node: h1 = relu(agg1 + x@root1 + b1) ----------------
__global__ void l1_node(const float* __restrict__ x, const float* __restrict__ agg,
                        const float* __restrict__ root, const float* __restrict__ bias,
                        float* __restrict__ h, int N) {
    int n = blockIdx.x * blockDim.x + threadIdx.x;
    if (n >= N) return;
    float x0 = x[n * 3 + 0], x1 = x[n * 3 + 1], x2 = x[n * 3 + 2];
#pragma unroll
    for (int j = 0; j < 6; j++) {
        float v = agg[n * 6 + j] + x0 * root[j] + x1 * root[6 + j] + x2 * root[12 + j] + bias[j];
        h[n * 6 + j] = frelu(v);
    }
}

// ---------------- layer 2 edge: h1[N,6] -> agg2[N,3], sum aggr ----------------
__global__ void l2_edge(const int* __restrict__ src, const int* __restrict__ dst,
                        const int* __restrict__ et, const float* __restrict__ h1,
                        const float* __restrict__ W, float* __restrict__ agg, int E) {
    __shared__ float w[WSZ];
    for (int i = threadIdx.x; i < WSZ; i += blockDim.x) w[i] = W[i];
    __syncthreads();
    int e = blockIdx.x * blockDim.x + threadIdx.x;
    if (e >= E) return;
    int s = src[e], d = dst[e], t = et[e];
    const float* hv = &h1[s * 6];
    const float* wt = &w[t * 6];
    float* a = &agg[d * 3];
    // msg[b] = sum_i h1[b*2+i] * W[et, b, i, 0]
    unsafeAtomicAdd(&a[0], hv[0] * wt[0] + hv[1] * wt[1]);
    unsafeAtomicAdd(&a[1], hv[2] * wt[2] + hv[3] * wt[3]);
    unsafeAtomicAdd(&a[2], hv[4] * wt[4] + hv[5] * wt[5]);
}

// ---------------- layer 2 node: h2 = relu(agg2 + h1@root2 + b2) ----------------
__global__ void l2_node(const float* __restrict__ h1, const float* __restrict__ agg,
                        const float* __restrict__ root, const float* __restrict__ bias,
                        float* __restrict__ h2, int N) {
    int n = blockIdx.x * blockDim.x + threadIdx.x;
    if (n >= N) return;
    float hv[6];
#pragma unroll
    for (int k = 0; k < 6; k++) hv[k] = h1[n * 6 + k];
#pragma unroll
    for (int j = 0; j < 3; j++) {
        float v = agg[n * 3 + j] + bias[j];
#pragma unroll
        for (int k = 0; k < 6; k++) v += hv[k] * root[k * 3 + j];
        h2[n * 3 + j] = frelu(v);
    }
}

// ---------------- layer 3 edge: h2[N,3] -> agg3[N,6], mean norm via cached rinv ----------------
__global__ void l3_edge(const int* __restrict__ src, const int* __restrict__ dst,
                        const int* __restrict__ et, const float* __restrict__ h2,
                        const float* __restrict__ W, const float* __restrict__ rinv,
                        float* __restrict__ agg, int E) {
    __shared__ float w[WSZ];
    for (int i = threadIdx.x; i < WSZ; i += blockDim.x) w[i] = W[i];
    __syncthreads();
    int e = blockIdx.x * blockDim.x + threadIdx.x;
    if (e >= E) return;
    int s = src[e], d = dst[e], t = et[e];
    float r = rinv[e];
    float x0 = h2[s * 3 + 0], x1 = h2[s * 3 + 1], x2 = h2[s * 3 + 2];
    const float* wt = &w[t * 6];
    float* a = &agg[d * 6];
    unsafeAtomicAdd(&a[0], x0 * wt[0] * r);
    unsafeAtomicAdd(&a[1], x0 * wt[1] * r);
    unsafeAtomicAdd(&a[2], x1 * wt[2] * r);
    unsafeAtomicAdd(&a[3], x1 * wt[3] * r);
    unsafeAtomicAdd(&a[4], x2 * wt[4] * r);
    unsafeAtomicAdd(&a[5], x2 * wt[5] * r);
}

// ---------------- layer 3 node + global mean pool accumulation ----------------
__global__ void l3_node_pool(const float* __restrict__ h2, const float* __restrict__ agg,
                             const float* __restrict__ root, const float* __restrict__ bias,
                             const int* __restrict__ batch, float* __restrict__ pooled, int N) {
    int n = blockIdx.x * blockDim.x + threadIdx.x;
    float v[6];
    float c = 0.0f;
#pragma unroll
    for (int j = 0; j < 6; j++) v[j] = 0.0f;
    if (n < N && batch[n] == 0) {
        c = 1.0f;
        float x0 = h2[n * 3 + 0], x1 = h2[n * 3 + 1], x2 = h2[n * 3 + 2];
#pragma unroll
        for (int j = 0; j < 6; j++) {
            float t = agg[n * 6 + j] + x0 * root[j] + x1 * root[6 + j] + x2 * root[12 + j] + bias[j];
            v[j] = frelu(t);
        }
    }
    // wave-64 reduce
#pragma unroll
    for (int off = 32; off > 0; off >>= 1) {
#pragma unroll
        for (int j = 0; j < 6; j++) v[j] += __shfl_down(v[j], off);
        c += __shfl_down(c, off);
    }
    __shared__ float sm[4][8];
    int wave = threadIdx.x >> 6, lane = threadIdx.x & 63;
    if (lane == 0) {
#pragma unroll
        for (int j = 0; j < 6; j++) sm[wave][j] = v[j];
        sm[wave][6] = c;
    }
    __syncthreads();
    if (threadIdx.x == 0) {
#pragma unroll
        for (int k = 0; k < 7; k++) {
            float t = sm[0][k] + sm[1][k] + sm[2][k] + sm[3][k];
            unsafeAtomicAdd(&pooled[k], t);
        }
    }
}

// ---------------- finalize: mean + log_softmax over 6 values ----------------
__global__ void finalize_kernel(const float* __restrict__ pooled, float* __restrict__ out) {
    if (threadIdx.x == 0) {
        float c = pooled[6];
        if (c < 1.0f) c = 1.0f;
        float p[6];
        float m = -1e30f;
#pragma unroll
        for (int j = 0; j < 6; j++) { p[j] = pooled[j] / c; m = fmaxf(m, p[j]); }
        float s = 0.0f;
#pragma unroll
        for (int j = 0; j < 6; j++) s += expf(p[j] - m);
        float lse = m + logf(s);
#pragma unroll
        for (int j = 0; j < 6; j++) out[j] = p[j] - lse;
    }
}

extern "C" void kernel_launch(void* const* d_in, const int* in_sizes, int n_in,
                              void* d_out, int out_size, void* d_ws, size_t ws_size,
                              hipStream_t stream) {
    const float* x     = (const float*)d_in[0];
    const int*   ei    = (const int*)d_in[1];
    const int*   batch = (const int*)d_in[2];
    const int*   etype = (const int*)d_in[3];
    const float* W1    = (const float*)d_in[4];
    const float* root1 = (const float*)d_in[5];
    const float* b1    = (const float*)d_in[6];
    const float* W2    = (const float*)d_in[7];
    const float* root2 = (const float*)d_in[8];
    const float* b2    = (const float*)d_in[9];
    const float* W3    = (const float*)d_in[10];
    const float* root3 = (const float*)d_in[11];
    const float* b3    = (const float*)d_in[12];

    const int N = in_sizes[0] / 3;
    const int E = in_sizes[1] / 2;
    const int* src = ei;
    const int* dst = ei + E;

    // workspace layout (256B aligned slots)
    char* ws = (char*)d_ws;
    size_t off = 0;
    auto alloc = [&](size_t bytes) -> void* {
        void* p = ws + off;
        off += (bytes + 255) & ~(size_t)255;
        return p;
    };
    int*   cnt    = (int*)  alloc((size_t)N * NREL * sizeof(int));   // 36 MB
    float* agg1   = (float*)alloc((size_t)N * 6 * sizeof(float));
    float* agg2   = (float*)alloc((size_t)N * 3 * sizeof(float));
    float* agg3   = (float*)alloc((size_t)N * 6 * sizeof(float));
    float* pooled = (float*)alloc(8 * sizeof(float));
    size_t zero_bytes = off;                                          // all above must start at 0
    float* rinv   = (float*)alloc((size_t)E * sizeof(float));         // fully overwritten
    float* h1     = (float*)alloc((size_t)N * 6 * sizeof(float));     // fully overwritten
    float* h2     = (float*)alloc((size_t)N * 3 * sizeof(float));     // fully overwritten

    hipMemsetAsync(d_ws, 0, zero_bytes, stream);

    const int TB = 256;
    const int gE = (E + TB - 1) / TB;
    const int gN = (N + TB - 1) / TB;

    count_kernel<<<gE, TB, 0, stream>>>(dst, etype, cnt, E);
    l1_edge<<<gE, TB, 0, stream>>>(src, dst, etype, x, W1, cnt, rinv, agg1, E);
    l1_node<<<gN, TB, 0, stream>>>(x, agg1, root1, b1, h1, N);
    l2_edge<<<gE, TB, 0, stream>>>(src, dst, etype, h1, W2, agg2, E);
    l2_node<<<gN, TB, 0, stream>>>(h1, agg2, root2, b2, h2, N);
    l3_edge<<<gE, TB, 0, stream>>>(src, dst, etype, h2, W3, rinv, agg3, E);
    l3_node_pool<<<gN, TB, 0, stream>>>(h2, agg3, root3, b3, batch, pooled, N);
    finalize_kernel<<<1, 64, 0, stream>>>(pooled, (float*)d_out);
}

// Round 2
// 957.703 us; speedup vs baseline: 5.3780x; 5.3780x over previous
//
#include <hip/hip_runtime.h>

// RGCN sort-then-gather design.
// Phase 1: build dst-sorted CSR (deg histogram -> exclusive scan -> scatter).
// Phase 2: each layer = one wave per dst node; lanes stream the node's edge
// segment (contiguous), accumulate in registers, shuffle-reduce; lane 0 adds
// root term + bias + relu and writes. No fp32 atomics anywhere.
// Per-(dst,rel) mean counts: per-wave LDS histogram (90 bins) in layer 1,
// cached as rinvA per sorted edge and re-read in layer 3.

#define NREL 90
#define WSZ  540   // R*NB*in_b*out_b = 540 floats for every layer here

__device__ __forceinline__ float frelu(float v) { return v > 0.0f ? v : 0.0f; }

// ---------- phase 1a: dst degree histogram ----------
__global__ void deg_kernel(const int* __restrict__ dst, int* __restrict__ deg, int E) {
    int e = blockIdx.x * blockDim.x + threadIdx.x;
    if (e < E) atomicAdd(&deg[dst[e]], 1);
}

// ---------- phase 1b: exclusive scan (3-kernel) ----------
__global__ void scan1(const int* __restrict__ deg, int* __restrict__ rowptr,
                      int* __restrict__ bsum, int N) {
    __shared__ int sm[1024];
    int i = blockIdx.x * 1024 + threadIdx.x;
    int v = (i < N) ? deg[i] : 0;
    sm[threadIdx.x] = v;
    __syncthreads();
    for (int off = 1; off < 1024; off <<= 1) {
        int t = (threadIdx.x >= off) ? sm[threadIdx.x - off] : 0;
        __syncthreads();
        sm[threadIdx.x] += t;
        __syncthreads();
    }
    if (i < N) rowptr[i] = sm[threadIdx.x] - v;     // exclusive
    if (threadIdx.x == 1023) bsum[blockIdx.x] = sm[1023];
}

__global__ void scan2(int* __restrict__ bsum, int nb) {
    __shared__ int sm[1024];
    int v = (threadIdx.x < nb) ? bsum[threadIdx.x] : 0;
    sm[threadIdx.x] = v;
    __syncthreads();
    for (int off = 1; off < 1024; off <<= 1) {
        int t = (threadIdx.x >= off) ? sm[threadIdx.x - off] : 0;
        __syncthreads();
        sm[threadIdx.x] += t;
        __syncthreads();
    }
    if (threadIdx.x < nb) bsum[threadIdx.x] = sm[threadIdx.x] - v;  // exclusive
}

__global__ void scan3(int* __restrict__ rowptr, const int* __restrict__ bsum,
                      int* __restrict__ next, int N, int E) {
    int i = blockIdx.x * blockDim.x + threadIdx.x;
    if (i < N) {
        int r = rowptr[i] + bsum[i >> 10];
        rowptr[i] = r;
        next[i] = r;
    }
    if (i == 0) rowptr[N] = E;
}

// ---------- phase 1c: scatter edges into dst-sorted order ----------
__global__ void scatter_kernel(const int* __restrict__ src, const int* __restrict__ dst,
                               const int* __restrict__ et, int* __restrict__ next,
                               int2* __restrict__ edgeA, int E) {
    int e = blockIdx.x * blockDim.x + threadIdx.x;
    if (e >= E) return;
    int d = dst[e];
    int p = atomicAdd(&next[d], 1);
    edgeA[p] = make_int2(src[e], et[e]);
}

// ---------- layer 1: wave per dst; LDS rel-histogram for mean; fused node ----------
__global__ void l1_gather(const int* __restrict__ rowptr, const int2* __restrict__ edgeA,
                          const float* __restrict__ x, const float* __restrict__ W,
                          const float* __restrict__ root, const float* __restrict__ bias,
                          float* __restrict__ rinvA, float* __restrict__ h1, int N) {
    __shared__ float w[WSZ];
    __shared__ int hist[4][NREL];
    for (int i = threadIdx.x; i < WSZ; i += blockDim.x) w[i] = W[i];
    __syncthreads();
    int wv = threadIdx.x >> 6, lane = threadIdx.x & 63;
    int d = blockIdx.x * 4 + wv;
    if (d >= N) return;
    int beg = rowptr[d], end = rowptr[d + 1];
    // per-wave relation histogram (same-wave DS ops execute in order; no barrier)
    for (int i = lane; i < NREL; i += 64) hist[wv][i] = 0;
    for (int i = beg + lane; i < end; i += 64) atomicAdd(&hist[wv][edgeA[i].y], 1);
    float a0 = 0, a1 = 0, a2 = 0, a3 = 0, a4 = 0, a5 = 0;
    for (int i = beg + lane; i < end; i += 64) {
        int2 st = edgeA[i];
        float r = 1.0f / (float)hist[wv][st.y];
        rinvA[i] = r;
        const float* wt = &w[st.y * 6];
        float x0 = x[st.x * 3 + 0] * r, x1 = x[st.x * 3 + 1] * r, x2 = x[st.x * 3 + 2] * r;
        a0 += x0 * wt[0]; a1 += x0 * wt[1];
        a2 += x1 * wt[2]; a3 += x1 * wt[3];
        a4 += x2 * wt[4]; a5 += x2 * wt[5];
    }
#pragma unroll
    for (int off = 32; off > 0; off >>= 1) {
        a0 += __shfl_down(a0, off); a1 += __shfl_down(a1, off); a2 += __shfl_down(a2, off);
        a3 += __shfl_down(a3, off); a4 += __shfl_down(a4, off); a5 += __shfl_down(a5, off);
    }
    if (lane == 0) {
        float x0 = x[d * 3 + 0], x1 = x[d * 3 + 1], x2 = x[d * 3 + 2];
        float o[6] = {a0, a1, a2, a3, a4, a5};
#pragma unroll
        for (int j = 0; j < 6; j++)
            h1[d * 6 + j] = frelu(o[j] + x0 * root[j] + x1 * root[6 + j] + x2 * root[12 + j] + bias[j]);
    }
}

// ---------- layer 2: wave per dst, sum aggr, fused node ----------
__global__ void l2_gather(const int* __restrict__ rowptr, const int2* __restrict__ edgeA,
                          const float* __restrict__ h1, const float* __restrict__ W,
                          const float* __restrict__ root, const float* __restrict__ bias,
                          float* __restrict__ h2, int N) {
    __shared__ float w[WSZ];
    for (int i = threadIdx.x; i < WSZ; i += blockDim.x) w[i] = W[i];
    __syncthreads();
    int wv = threadIdx.x >> 6, lane = threadIdx.x & 63;
    int d = blockIdx.x * 4 + wv;
    if (d >= N) return;
    int beg = rowptr[d], end = rowptr[d + 1];
    float a0 = 0, a1 = 0, a2 = 0;
    for (int i = beg + lane; i < end; i += 64) {
        int2 st = edgeA[i];
        const float* hv = &h1[st.x * 6];
        const float* wt = &w[st.y * 6];
        a0 += hv[0] * wt[0] + hv[1] * wt[1];
        a1 += hv[2] * wt[2] + hv[3] * wt[3];
        a2 += hv[4] * wt[4] + hv[5] * wt[5];
    }
#pragma unroll
    for (int off = 32; off > 0; off >>= 1) {
        a0 += __shfl_down(a0, off); a1 += __shfl_down(a1, off); a2 += __shfl_down(a2, off);
    }
    if (lane == 0) {
        float hv[6];
#pragma unroll
        for (int k = 0; k < 6; k++) hv[k] = h1[d * 6 + k];
        float o[3] = {a0, a1, a2};
#pragma unroll
        for (int j = 0; j < 3; j++) {
            float v = o[j] + bias[j];
#pragma unroll
            for (int k = 0; k < 6; k++) v += hv[k] * root[k * 3 + j];
            h2[d * 3 + j] = frelu(v);
        }
    }
}

// ---------- layer 3: wave per dst, mean via cached rinv, fused node + pool partials ----------
__global__ void l3_gather_pool(const int* __restrict__ rowptr, const int2* __restrict__ edgeA,
                               const float* __restrict__ rinvA, const float* __restrict__ h2,
                               const float* __restrict__ W, const float* __restrict__ root,
                               const float* __restrict__ bias, const int* __restrict__ batch,
                               float* __restrict__ partials, int N) {
    __shared__ float w[WSZ];
    __shared__ float sm[4][8];
    for (int i = threadIdx.x; i < WSZ; i += blockDim.x) w[i] = W[i];
    __syncthreads();
    int wv = threadIdx.x >> 6, lane = threadIdx.x & 63;
    int d = blockIdx.x * 4 + wv;
    float a0 = 0, a1 = 0, a2 = 0, a3 = 0, a4 = 0, a5 = 0;
    if (d < N) {
        int beg = rowptr[d], end = rowptr[d + 1];
        for (int i = beg + lane; i < end; i += 64) {
            int2 st = edgeA[i];
            float r = rinvA[i];
            const float* wt = &w[st.y * 6];
            float x0 = h2[st.x * 3 + 0] * r, x1 = h2[st.x * 3 + 1] * r, x2 = h2[st.x * 3 + 2] * r;
            a0 += x0 * wt[0]; a1 += x0 * wt[1];
            a2 += x1 * wt[2]; a3 += x1 * wt[3];
            a4 += x2 * wt[4]; a5 += x2 * wt[5];
        }
    }
#pragma unroll
    for (int off = 32; off > 0; off >>= 1) {
        a0 += __shfl_down(a0, off); a1 += __shfl_down(a1, off); a2 += __shfl_down(a2, off);
        a3 += __shfl_down(a3, off); a4 += __shfl_down(a4, off); a5 += __shfl_down(a5, off);
    }
    if (lane == 0) {
        float v[7] = {0, 0, 0, 0, 0, 0, 0};
        if (d < N && batch[d] == 0) {
            float x0 = h2[d * 3 + 0], x1 = h2[d * 3 + 1], x2 = h2[d * 3 + 2];
            float o[6] = {a0, a1, a2, a3, a4, a5};
#pragma unroll
            for (int j = 0; j < 6; j++)
                v[j] = frelu(o[j] + x0 * root[j] + x1 * root[6 + j] + x2 * root[12 + j] + bias[j]);
            v[6] = 1.0f;
        }
#pragma unroll
        for (int k = 0; k < 7; k++) sm[wv][k] = v[k];
    }
    __syncthreads();
    if (threadIdx.x == 0) {
#pragma unroll
        for (int k = 0; k < 7; k++)
            partials[(size_t)blockIdx.x * 8 + k] = sm[0][k] + sm[1][k] + sm[2][k] + sm[3][k];
    }
}

// ---------- pool reduce + log_softmax ----------
__global__ void pool_finalize(const float* __restrict__ partials, int nb, float* __restrict__ out) {
    float v[7] = {0, 0, 0, 0, 0, 0, 0};
    for (int b = threadIdx.x; b < nb; b += blockDim.x) {
#pragma unroll
        for (int k = 0; k < 7; k++) v[k] += partials[(size_t)b * 8 + k];
    }
#pragma unroll
    for (int off = 32; off > 0; off >>= 1) {
#pragma unroll
        for (int k = 0; k < 7; k++) v[k] += __shfl_down(v[k], off);
    }
    __shared__ float sm[16][8];
    int wv = threadIdx.x >> 6, lane = threadIdx.x & 63;
    if (lane == 0) {
#pragma unroll
        for (int k = 0; k < 7; k++) sm[wv][k] = v[k];
    }
    __syncthreads();
    if (threadIdx.x == 0) {
        float t[7] = {0, 0, 0, 0, 0, 0, 0};
        int nw = blockDim.x >> 6;
        for (int q = 0; q < nw; q++) {
#pragma unroll
            for (int k = 0; k < 7; k++) t[k] += sm[q][k];
        }
        float c = t[6] < 1.0f ? 1.0f : t[6];
        float p[6], m = -1e30f;
#pragma unroll
        for (int j = 0; j < 6; j++) { p[j] = t[j] / c; m = fmaxf(m, p[j]); }
        float s = 0.0f;
#pragma unroll
        for (int j = 0; j < 6; j++) s += expf(p[j] - m);
        float lse = m + logf(s);
#pragma unroll
        for (int j = 0; j < 6; j++) out[j] = p[j] - lse;
    }
}

extern "C" void kernel_launch(void* const* d_in, const int* in_sizes, int n_in,
                              void* d_out, int out_size, void* d_ws, size_t ws_size,
                              hipStream_t stream) {
    const float* x     = (const float*)d_in[0];
    const int*   ei    = (const int*)d_in[1];
    const int*   batch = (const int*)d_in[2];
    const int*   etype = (const int*)d_in[3];
    const float* W1    = (const float*)d_in[4];
    const float* root1 = (const float*)d_in[5];
    const float* b1    = (const float*)d_in[6];
    const float* W2    = (const float*)d_in[7];
    const float* root2 = (const float*)d_in[8];
    const float* b2    = (const float*)d_in[9];
    const float* W3    = (const float*)d_in[10];
    const float* root3 = (const float*)d_in[11];
    const float* b3    = (const float*)d_in[12];

    const int N = in_sizes[0] / 3;
    const int E = in_sizes[1] / 2;
    const int* src = ei;
    const int* dst = ei + E;

    char* ws = (char*)d_ws;
    size_t off = 0;
    auto alloc = [&](size_t bytes) -> void* {
        void* p = ws + off;
        off += (bytes + 255) & ~(size_t)255;
        return p;
    };
    int*   deg     = (int*)  alloc((size_t)N * sizeof(int));          // must be zeroed
    size_t zero_bytes = off;
    int*   rowptr  = (int*)  alloc((size_t)(N + 1) * sizeof(int));
    int*   next    = (int*)  alloc((size_t)(N + 1) * sizeof(int));
    int*   bsum    = (int*)  alloc(1024 * sizeof(int));
    int2*  edgeA   = (int2*) alloc((size_t)E * sizeof(int2));          // 51.2 MB
    float* rinvA   = (float*)alloc((size_t)E * sizeof(float));         // 25.6 MB
    float* h1      = (float*)alloc((size_t)N * 6 * sizeof(float));
    float* h2      = (float*)alloc((size_t)N * 3 * sizeof(float));
    const int gW = (N + 3) / 4;                                        // wave-per-dst blocks
    float* partials = (float*)alloc((size_t)gW * 8 * sizeof(float));

    hipMemsetAsync(deg, 0, zero_bytes, stream);

    const int TB = 256;
    const int gE = (E + TB - 1) / TB;
    const int nb = (N + 1023) / 1024;

    deg_kernel<<<gE, TB, 0, stream>>>(dst, deg, E);
    scan1<<<nb, 1024, 0, stream>>>(deg, rowptr, bsum, N);
    scan2<<<1, 1024, 0, stream>>>(bsum, nb);
    scan3<<<nb, 1024, 0, stream>>>(rowptr, bsum, next, N, E);
    scatter_kernel<<<gE, TB, 0, stream>>>(src, dst, etype, next, edgeA, E);

    l1_gather<<<gW, TB, 0, stream>>>(rowptr, edgeA, x, W1, root1, b1, rinvA, h1, N);
    l2_gather<<<gW, TB, 0, stream>>>(rowptr, edgeA, h1, W2, root2, b2, h2, N);
    l3_gather_pool<<<gW, TB, 0, stream>>>(rowptr, edgeA, rinvA, h2, W3, root3, b3, batch,
                                          partials, N);
    pool_finalize<<<1, 1024, 0, stream>>>(partials, gW, (float*)d_out);
}

// Round 3
// 917.688 us; speedup vs baseline: 5.6125x; 1.0436x over previous
//
#include <hip/hip_runtime.h>

// RGCN via coarse bucketing + LDS accumulation (no per-dst CSR, no global fp32 atomics).
// Bucket = dst>>7 (128 nodes). Phase 1: bucket histogram -> scan -> LDS-staged
// grouping of edges into bucket-contiguous order (packed 4B records).
// Phase 2: one block per bucket per layer; stream bucket's edges, accumulate
// into LDS acc[128][out] with ds_add_f32; per-(dst,rel) mean counts via LDS
// u16-packed histogram (recomputed in L3; second stream of the bucket's edge
// slice hits L2). Node op + ReLU fused; layer 3 fused with global mean pool.

#define NREL   90
#define WSZ    540          // R*NB*in_b*out_b floats, all three layers
#define BSH    7            // bucket shift
#define BNODES 128          // nodes per bucket (1<<BSH)
#define NBINS  1024         // padded bucket count (N<=131072)
#define CHUNK  8192         // edges per grouping block

__device__ __forceinline__ float frelu(float v) { return v > 0.0f ? v : 0.0f; }

// ---------- K0: pad x[N,3] -> x4[N] float4 ----------
__global__ void padx_k(const float* __restrict__ x, float4* __restrict__ x4, int N) {
    int i = blockIdx.x * 256 + threadIdx.x;
    if (i < N) x4[i] = make_float4(x[3 * i], x[3 * i + 1], x[3 * i + 2], 0.0f);
}

// ---------- K1: global bucket histogram (LDS-privatized) ----------
__global__ void bucket_hist_k(const int* __restrict__ dst, int* __restrict__ bhist, int E) {
    __shared__ int h[NBINS];
    int tid = threadIdx.x;
    for (int i = tid; i < NBINS; i += 256) h[i] = 0;
    __syncthreads();
    int e0 = blockIdx.x * CHUNK;
    int cnt = min(CHUNK, E - e0);
    for (int i = tid; i < cnt; i += 256) atomicAdd(&h[dst[e0 + i] >> BSH], 1);
    __syncthreads();
    for (int i = tid; i < NBINS; i += 256)
        if (h[i]) atomicAdd(&bhist[i], h[i]);
}

// ---------- K2: exclusive scan of 1024 bins (one wave, 16 bins/lane) ----------
__global__ void bucket_scan_k(const int* __restrict__ bhist, int* __restrict__ bbase,
                              int* __restrict__ gcursor) {
    int lane = threadIdx.x;  // 64 threads
    int loc[16];
    int s = 0;
    int b0 = lane * 16;
#pragma unroll
    for (int k = 0; k < 16; k++) { loc[k] = bhist[b0 + k]; s += loc[k]; }
    int inc = s;
#pragma unroll
    for (int off = 1; off < 64; off <<= 1) {
        int u = __shfl_up(inc, off);
        if (lane >= off) inc += u;
    }
    int run = inc - s;
#pragma unroll
    for (int k = 0; k < 16; k++) {
        bbase[b0 + k] = run;
        gcursor[b0 + k] = run;
        run += loc[k];
    }
}

// ---------- K3: LDS-staged grouping into bucket-contiguous packed records ----------
// record = src (17b) | rel<<17 (7b) | dstLocal<<24 (7b)
__launch_bounds__(256)
__global__ void group_k(const int* __restrict__ src, const int* __restrict__ dst,
                        const int* __restrict__ et, int* __restrict__ gcursor,
                        unsigned* __restrict__ grouped, int E) {
    __shared__ int s_hist[NBINS];
    __shared__ int s_cur[NBINS];                  // scan, then placement cursor
    __shared__ int s_gb2[NBINS];                  // global_base - scan
    __shared__ unsigned s_pack[CHUNK];
    __shared__ unsigned short s_bkt[CHUNK];
    int tid = threadIdx.x;
    for (int i = tid; i < NBINS; i += 256) s_hist[i] = 0;
    __syncthreads();
    int e0 = blockIdx.x * CHUNK;
    int cnt = min(CHUNK, E - e0);
    for (int i = tid; i < cnt; i += 256) atomicAdd(&s_hist[dst[e0 + i] >> BSH], 1);
    __syncthreads();
    if (tid < 64) {   // exclusive scan of s_hist -> s_cur (one wave, 16 bins/lane)
        int loc[16];
        int s = 0;
        int b0 = tid * 16;
#pragma unroll
        for (int k = 0; k < 16; k++) { loc[k] = s_hist[b0 + k]; s += loc[k]; }
        int inc = s;
#pragma unroll
        for (int off = 1; off < 64; off <<= 1) {
            int u = __shfl_up(inc, off);
            if (tid >= off) inc += u;
        }
        int run = inc - s;
#pragma unroll
        for (int k = 0; k < 16; k++) { s_cur[b0 + k] = run; run += loc[k]; }
    }
    __syncthreads();
    // reserve global ranges (one atomic per non-empty bucket per block)
    for (int i = tid; i < NBINS; i += 256) {
        int c = s_hist[i];
        int gb = c ? atomicAdd(&gcursor[i], c) : 0;
        s_gb2[i] = gb - s_cur[i];
    }
    __syncthreads();
    // place into LDS stage, grouped by bucket
    for (int i = tid; i < cnt; i += 256) {
        int e = e0 + i;
        int d = dst[e];
        int b = d >> BSH;
        int p = atomicAdd(&s_cur[b], 1);
        s_pack[p] = (unsigned)src[e] | ((unsigned)et[e] << 17) |
                    ((unsigned)(d & (BNODES - 1)) << 24);
        s_bkt[p] = (unsigned short)b;
    }
    __syncthreads();
    // coalesced write-out: consecutive stage positions -> consecutive global addrs
    for (int i = tid; i < cnt; i += 256) {
        int b = s_bkt[i];
        grouped[s_gb2[b] + i] = s_pack[i];
    }
}

// ---------- L1: mean aggr, x4 -> h1p[N][2]float4 ----------
__launch_bounds__(256)
__global__ void l1_k(const int* __restrict__ bbase, const unsigned* __restrict__ grouped,
                     const float4* __restrict__ x4, const float* __restrict__ W,
                     const float* __restrict__ root, const float* __restrict__ bias,
                     float4* __restrict__ h1p, int N) {
    __shared__ float w[WSZ];
    __shared__ float acc[BNODES * 6];
    __shared__ unsigned hist16[BNODES * 45];   // u16-packed [128][90] counts
    int tid = threadIdx.x;
    for (int i = tid; i < WSZ; i += 256) w[i] = W[i];
    for (int i = tid; i < BNODES * 6; i += 256) acc[i] = 0.0f;
    for (int i = tid; i < BNODES * 45; i += 256) hist16[i] = 0u;
    __syncthreads();
    int b = blockIdx.x;
    int e0 = bbase[b], e1 = bbase[b + 1];
    for (int e = e0 + tid; e < e1; e += 256) {
        unsigned p = grouped[e];
        unsigned idx = (p >> 24) * 90u + ((p >> 17) & 127u);
        atomicAdd(&hist16[idx >> 1], 1u << ((idx & 1) << 4));
    }
    __syncthreads();
    for (int e = e0 + tid; e < e1; e += 256) {
        unsigned p = grouped[e];
        unsigned s = p & 0x1FFFFu;
        unsigned rel = (p >> 17) & 127u;
        unsigned dL = p >> 24;
        unsigned idx = dL * 90u + rel;
        unsigned c = (hist16[idx >> 1] >> ((idx & 1) << 4)) & 0xFFFFu;
        float r = 1.0f / (float)c;
        float4 xv = x4[s];
        const float* wt = &w[rel * 6];
        float* a = &acc[dL * 6];
        float x0 = xv.x * r, x1 = xv.y * r, x2 = xv.z * r;
        atomicAdd(&a[0], x0 * wt[0]);
        atomicAdd(&a[1], x0 * wt[1]);
        atomicAdd(&a[2], x1 * wt[2]);
        atomicAdd(&a[3], x1 * wt[3]);
        atomicAdd(&a[4], x2 * wt[4]);
        atomicAdd(&a[5], x2 * wt[5]);
    }
    __syncthreads();
    int n0 = b << BSH;
    int d = n0 + tid;
    if (tid < BNODES && d < N) {
        float4 xv = x4[d];
        float o[6];
#pragma unroll
        for (int j = 0; j < 6; j++)
            o[j] = frelu(acc[tid * 6 + j] + xv.x * root[j] + xv.y * root[6 + j] +
                         xv.z * root[12 + j] + bias[j]);
        h1p[d * 2]     = make_float4(o[0], o[1], o[2], o[3]);
        h1p[d * 2 + 1] = make_float4(o[4], o[5], 0.0f, 0.0f);
    }
}

// ---------- L2: sum aggr, h1p -> h2p[N]float4 ----------
__launch_bounds__(256)
__global__ void l2_k(const int* __restrict__ bbase, const unsigned* __restrict__ grouped,
                     const float4* __restrict__ h1p, const float* __restrict__ W,
                     const float* __restrict__ root, const float* __restrict__ bias,
                     float4* __restrict__ h2p, int N) {
    __shared__ float w[WSZ];
    __shared__ float acc[BNODES * 3];
    int tid = threadIdx.x;
    for (int i = tid; i < WSZ; i += 256) w[i] = W[i];
    for (int i = tid; i < BNODES * 3; i += 256) acc[i] = 0.0f;
    __syncthreads();
    int b = blockIdx.x;
    int e0 = bbase[b], e1 = bbase[b + 1];
    for (int e = e0 + tid; e < e1; e += 256) {
        unsigned p = grouped[e];
        unsigned s = p & 0x1FFFFu;
        unsigned rel = (p >> 17) & 127u;
        unsigned dL = p >> 24;
        float4 ha = h1p[s * 2];
        float4 hb = h1p[s * 2 + 1];
        const float* wt = &w[rel * 6];
        float* a = &acc[dL * 3];
        atomicAdd(&a[0], ha.x * wt[0] + ha.y * wt[1]);
        atomicAdd(&a[1], ha.z * wt[2] + ha.w * wt[3]);
        atomicAdd(&a[2], hb.x * wt[4] + hb.y * wt[5]);
    }
    __syncthreads();
    int n0 = b << BSH;
    int d = n0 + tid;
    if (tid < BNODES && d < N) {
        float4 ha = h1p[d * 2];
        float4 hb = h1p[d * 2 + 1];
        float hv[6] = {ha.x, ha.y, ha.z, ha.w, hb.x, hb.y};
        float o[3];
#pragma unroll
        for (int j = 0; j < 3; j++) {
            float v = acc[tid * 3 + j] + bias[j];
#pragma unroll
            for (int k = 0; k < 6; k++) v += hv[k] * root[k * 3 + j];
            o[j] = frelu(v);
        }
        h2p[d] = make_float4(o[0], o[1], o[2], 0.0f);
    }
}

// ---------- L3: mean aggr + fused node op + global-mean-pool partials ----------
__launch_bounds__(256)
__global__ void l3_k(const int* __restrict__ bbase, const unsigned* __restrict__ grouped,
                     const float4* __restrict__ h2p, const float* __restrict__ W,
                     const float* __restrict__ root, const float* __restrict__ bias,
                     const int* __restrict__ batch, float* __restrict__ partials, int N) {
    __shared__ float w[WSZ];
    __shared__ float acc[BNODES * 6];
    __shared__ unsigned hist16[BNODES * 45];
    __shared__ float redsm[4][8];
    int tid = threadIdx.x;
    for (int i = tid; i < WSZ; i += 256) w[i] = W[i];
    for (int i = tid; i < BNODES * 6; i += 256) acc[i] = 0.0f;
    for (int i = tid; i < BNODES * 45; i += 256) hist16[i] = 0u;
    __syncthreads();
    int b = blockIdx.x;
    int e0 = bbase[b], e1 = bbase[b + 1];
    for (int e = e0 + tid; e < e1; e += 256) {
        unsigned p = grouped[e];
        unsigned idx = (p >> 24) * 90u + ((p >> 17) & 127u);
        atomicAdd(&hist16[idx >> 1], 1u << ((idx & 1) << 4));
    }
    __syncthreads();
    for (int e = e0 + tid; e < e1; e += 256) {
        unsigned p = grouped[e];
        unsigned s = p & 0x1FFFFu;
        unsigned rel = (p >> 17) & 127u;
        unsigned dL = p >> 24;
        unsigned idx = dL * 90u + rel;
        unsigned c = (hist16[idx >> 1] >> ((idx & 1) << 4)) & 0xFFFFu;
        float r = 1.0f / (float)c;
        float4 xv = h2p[s];
        const float* wt = &w[rel * 6];
        float* a = &acc[dL * 6];
        float x0 = xv.x * r, x1 = xv.y * r, x2 = xv.z * r;
        atomicAdd(&a[0], x0 * wt[0]);
        atomicAdd(&a[1], x0 * wt[1]);
        atomicAdd(&a[2], x1 * wt[2]);
        atomicAdd(&a[3], x1 * wt[3]);
        atomicAdd(&a[4], x2 * wt[4]);
        atomicAdd(&a[5], x2 * wt[5]);
    }
    __syncthreads();
    int n0 = b << BSH;
    int d = n0 + tid;
    float v[7] = {0, 0, 0, 0, 0, 0, 0};
    if (tid < BNODES && d < N && batch[d] == 0) {
        float4 xv = h2p[d];
#pragma unroll
        for (int j = 0; j < 6; j++)
            v[j] = frelu(acc[tid * 6 + j] + xv.x * root[j] + xv.y * root[6 + j] +
                         xv.z * root[12 + j] + bias[j]);
        v[6] = 1.0f;
    }
#pragma unroll
    for (int off = 32; off > 0; off >>= 1) {
#pragma unroll
        for (int k = 0; k < 7; k++) v[k] += __shfl_down(v[k], off);
    }
    int wv = tid >> 6, lane = tid & 63;
    if (lane == 0) {
#pragma unroll
        for (int k = 0; k < 7; k++) redsm[wv][k] = v[k];
    }
    __syncthreads();
    if (tid == 0) {
#pragma unroll
        for (int k = 0; k < 7; k++)
            partials[(size_t)b * 8 + k] = redsm[0][k] + redsm[1][k] + redsm[2][k] + redsm[3][k];
    }
}

// ---------- finalize: reduce partials + log_softmax ----------
__global__ void pool_finalize(const float* __restrict__ partials, int nb,
                              float* __restrict__ out) {
    float v[7] = {0, 0, 0, 0, 0, 0, 0};
    for (int b = threadIdx.x; b < nb; b += blockDim.x) {
#pragma unroll
        for (int k = 0; k < 7; k++) v[k] += partials[(size_t)b * 8 + k];
    }
#pragma unroll
    for (int off = 32; off > 0; off >>= 1) {
#pragma unroll
        for (int k = 0; k < 7; k++) v[k] += __shfl_down(v[k], off);
    }
    __shared__ float sm[16][8];
    int wv = threadIdx.x >> 6, lane = threadIdx.x & 63;
    if (lane == 0) {
#pragma unroll
        for (int k = 0; k < 7; k++) sm[wv][k] = v[k];
    }
    __syncthreads();
    if (threadIdx.x == 0) {
        float t[7] = {0, 0, 0, 0, 0, 0, 0};
        int nw = blockDim.x >> 6;
        for (int q = 0; q < nw; q++) {
#pragma unroll
            for (int k = 0; k < 7; k++) t[k] += sm[q][k];
        }
        float c = t[6] < 1.0f ? 1.0f : t[6];
        float p[6], m = -1e30f;
#pragma unroll
        for (int j = 0; j < 6; j++) { p[j] = t[j] / c; m = fmaxf(m, p[j]); }
        float s = 0.0f;
#pragma unroll
        for (int j = 0; j < 6; j++) s += expf(p[j] - m);
        float lse = m + logf(s);
#pragma unroll
        for (int j = 0; j < 6; j++) out[j] = p[j] - lse;
    }
}

extern "C" void kernel_launch(void* const* d_in, const int* in_sizes, int n_in,
                              void* d_out, int out_size, void* d_ws, size_t ws_size,
                              hipStream_t stream) {
    const float* x     = (const float*)d_in[0];
    const int*   ei    = (const int*)d_in[1];
    const int*   batch = (const int*)d_in[2];
    const int*   etype = (const int*)d_in[3];
    const float* W1    = (const float*)d_in[4];
    const float* root1 = (const float*)d_in[5];
    const float* b1    = (const float*)d_in[6];
    const float* W2    = (const float*)d_in[7];
    const float* root2 = (const float*)d_in[8];
    const float* b2    = (const float*)d_in[9];
    const float* W3    = (const float*)d_in[10];
    const float* root3 = (const float*)d_in[11];
    const float* b3    = (const float*)d_in[12];

    const int N = in_sizes[0] / 3;
    const int E = in_sizes[1] / 2;
    const int* src = ei;
    const int* dst = ei + E;

    char* ws = (char*)d_ws;
    size_t off = 0;
    auto alloc = [&](size_t bytes) -> void* {
        void* p = ws + off;
        off += (bytes + 255) & ~(size_t)255;
        return p;
    };
    int*      bhist   = (int*)     alloc(NBINS * sizeof(int));           // must be zeroed
    size_t zero_bytes = off;
    int*      bbase   = (int*)     alloc((NBINS + 1) * sizeof(int));
    int*      gcursor = (int*)     alloc(NBINS * sizeof(int));
    unsigned* grouped = (unsigned*)alloc((size_t)E * sizeof(unsigned));  // 25.6 MB
    float4*   x4      = (float4*)  alloc((size_t)N * sizeof(float4));
    float4*   h1p     = (float4*)  alloc((size_t)N * 2 * sizeof(float4));
    float4*   h2p     = (float4*)  alloc((size_t)N * sizeof(float4));
    const int NBUCK = (N + BNODES - 1) >> BSH;                           // 782
    float*    partials = (float*)  alloc((size_t)NBUCK * 8 * sizeof(float));

    hipMemsetAsync(bhist, 0, zero_bytes, stream);

    const int gN = (N + 255) / 256;
    const int gC = (E + CHUNK - 1) / CHUNK;

    padx_k<<<gN, 256, 0, stream>>>(x, x4, N);
    bucket_hist_k<<<gC, 256, 0, stream>>>(dst, bhist, E);
    bucket_scan_k<<<1, 64, 0, stream>>>(bhist, bbase, gcursor);
    group_k<<<gC, 256, 0, stream>>>(src, dst, etype, gcursor, grouped, E);

    l1_k<<<NBUCK, 256, 0, stream>>>(bbase, grouped, x4, W1, root1, b1, h1p, N);
    l2_k<<<NBUCK, 256, 0, stream>>>(bbase, grouped, h1p, W2, root2, b2, h2p, N);
    l3_k<<<NBUCK, 256, 0, stream>>>(bbase, grouped, h2p, W3, root3, b3, batch, partials, N);
    pool_finalize<<<1, 1024, 0, stream>>>(partials, NBUCK, (float*)d_out);
}

// Round 4
// 802.552 us; speedup vs baseline: 6.4177x; 1.1435x over previous
//
#include <hip/hip_runtime.h>

// RGCN, bucketed gather + LDS accumulation, latency-optimized:
//  - bucket = dst>>7 (128 nodes); edges grouped bucket-contiguous (packed 4B records)
//  - L1: one block/bucket (512 thr): LDS (dst,rel)-hist -> rinvA cache + LDS acc + fused node
//  - L2/L3: 4 slice-blocks per bucket (256 thr), 1 pass, unrolled x4, LDS acc partial,
//    coalesced global fp32 atomic flush; node op as separate N-parallel kernel
//  - every edge loop unrolled x4 (batched loads) to break load->use dependent chains

#define NREL   90
#define WSZ    540          // R*NB*in_b*out_b floats, all three layers
#define BSH    7
#define BNODES 128
#define NBINS  1024         // padded bucket count
#define GCH    4096         // edges per grouping block
#define HCH    16384        // edges per hist block

__device__ __forceinline__ float frelu(float v) { return v > 0.0f ? v : 0.0f; }

// ---------- K0: pad x[N,3] -> float4 ----------
__global__ void padx_k(const float* __restrict__ x, float4* __restrict__ x4, int N) {
    int i = blockIdx.x * 256 + threadIdx.x;
    if (i < N) x4[i] = make_float4(x[3 * i], x[3 * i + 1], x[3 * i + 2], 0.0f);
}

// ---------- K1: global bucket histogram ----------
__launch_bounds__(512)
__global__ void bucket_hist_k(const int* __restrict__ dst, int* __restrict__ bhist, int E) {
    __shared__ int h[NBINS];
    int tid = threadIdx.x;
    for (int i = tid; i < NBINS; i += 512) h[i] = 0;
    __syncthreads();
    int e0 = blockIdx.x * HCH;
    int e1 = min(e0 + HCH, E);
    int e = e0 + tid;
    for (; e + 1536 < e1; e += 2048) {
        int d0 = dst[e], d1 = dst[e + 512], d2 = dst[e + 1024], d3 = dst[e + 1536];
        atomicAdd(&h[d0 >> BSH], 1); atomicAdd(&h[d1 >> BSH], 1);
        atomicAdd(&h[d2 >> BSH], 1); atomicAdd(&h[d3 >> BSH], 1);
    }
    for (; e < e1; e += 512) atomicAdd(&h[dst[e] >> BSH], 1);
    __syncthreads();
    for (int i = tid; i < NBINS; i += 512)
        if (h[i]) atomicAdd(&bhist[i], h[i]);
}

// ---------- K2: exclusive scan of 1024 bins (one wave) ----------
__global__ void bucket_scan_k(const int* __restrict__ bhist, int* __restrict__ bbase,
                              int* __restrict__ gcursor) {
    int lane = threadIdx.x;  // 64
    int loc[16];
    int s = 0;
    int b0 = lane * 16;
#pragma unroll
    for (int k = 0; k < 16; k++) { loc[k] = bhist[b0 + k]; s += loc[k]; }
    int inc = s;
#pragma unroll
    for (int off = 1; off < 64; off <<= 1) {
        int u = __shfl_up(inc, off);
        if (lane >= off) inc += u;
    }
    int run = inc - s;
#pragma unroll
    for (int k = 0; k < 16; k++) {
        bbase[b0 + k] = run;
        gcursor[b0 + k] = run;
        run += loc[k];
    }
}

// ---------- K3: LDS-staged grouping; record = src | rel<<17 | dstLocal<<24 ----------
__launch_bounds__(512)
__global__ void group_k(const int* __restrict__ src, const int* __restrict__ dst,
                        const int* __restrict__ et, int* __restrict__ gcursor,
                        unsigned* __restrict__ grouped, int E) {
    __shared__ int s_hist[NBINS];
    __shared__ int s_cur[NBINS];
    __shared__ int s_gb2[NBINS];
    __shared__ unsigned s_pack[GCH];
    __shared__ unsigned short s_bkt[GCH];
    int tid = threadIdx.x;
    for (int i = tid; i < NBINS; i += 512) s_hist[i] = 0;
    __syncthreads();
    int e0 = blockIdx.x * GCH;
    int cnt = min(GCH, E - e0);
    int i = tid;
    for (; i + 1536 < cnt; i += 2048) {
        int d0 = dst[e0 + i], d1 = dst[e0 + i + 512], d2 = dst[e0 + i + 1024], d3 = dst[e0 + i + 1536];
        atomicAdd(&s_hist[d0 >> BSH], 1); atomicAdd(&s_hist[d1 >> BSH], 1);
        atomicAdd(&s_hist[d2 >> BSH], 1); atomicAdd(&s_hist[d3 >> BSH], 1);
    }
    for (; i < cnt; i += 512) atomicAdd(&s_hist[dst[e0 + i] >> BSH], 1);
    __syncthreads();
    if (tid < 64) {   // exclusive scan
        int loc[16];
        int s = 0;
        int b0 = tid * 16;
#pragma unroll
        for (int k = 0; k < 16; k++) { loc[k] = s_hist[b0 + k]; s += loc[k]; }
        int inc = s;
#pragma unroll
        for (int off = 1; off < 64; off <<= 1) {
            int u = __shfl_up(inc, off);
            if (tid >= off) inc += u;
        }
        int run = inc - s;
#pragma unroll
        for (int k = 0; k < 16; k++) { s_cur[b0 + k] = run; run += loc[k]; }
    }
    __syncthreads();
    for (int q = tid; q < NBINS; q += 512) {
        int c = s_hist[q];
        int gb = c ? atomicAdd(&gcursor[q], c) : 0;
        s_gb2[q] = gb - s_cur[q];
    }
    __syncthreads();
    for (int q = tid; q < cnt; q += 512) {
        int e = e0 + q;
        int d = dst[e];
        int b = d >> BSH;
        int p = atomicAdd(&s_cur[b], 1);
        s_pack[p] = (unsigned)src[e] | ((unsigned)et[e] << 17) |
                    ((unsigned)(d & (BNODES - 1)) << 24);
        s_bkt[p] = (unsigned short)b;
    }
    __syncthreads();
    for (int q = tid; q < cnt; q += 512) {
        int b = s_bkt[q];
        grouped[s_gb2[b] + q] = s_pack[q];
    }
}

// ---------- L1: one block/bucket, hist -> rinvA + LDS acc + fused node ----------
__launch_bounds__(512)
__global__ void l1_k(const int* __restrict__ bbase, const unsigned* __restrict__ grouped,
                     const float4* __restrict__ x4, const float* __restrict__ W,
                     const float* __restrict__ root, const float* __restrict__ bias,
                     float* __restrict__ rinvA, float4* __restrict__ h1p, int N) {
    __shared__ float w[WSZ];
    __shared__ float acc[BNODES * 6];
    __shared__ unsigned hist16[BNODES * 45];   // u16-packed [128][90]
    int tid = threadIdx.x;
    for (int i = tid; i < WSZ; i += 512) w[i] = W[i];
    for (int i = tid; i < BNODES * 6; i += 512) acc[i] = 0.0f;
    for (int i = tid; i < BNODES * 45; i += 512) hist16[i] = 0u;
    __syncthreads();
    int b = blockIdx.x;
    int e0 = bbase[b], e1 = bbase[b + 1];
    // pass 1: (dstLocal, rel) histogram, unrolled
    int e = e0 + tid;
    for (; e + 1536 < e1; e += 2048) {
        unsigned p0 = grouped[e], p1 = grouped[e + 512], p2 = grouped[e + 1024], p3 = grouped[e + 1536];
        unsigned i0 = (p0 >> 24) * 90u + ((p0 >> 17) & 127u);
        unsigned i1 = (p1 >> 24) * 90u + ((p1 >> 17) & 127u);
        unsigned i2 = (p2 >> 24) * 90u + ((p2 >> 17) & 127u);
        unsigned i3 = (p3 >> 24) * 90u + ((p3 >> 17) & 127u);
        atomicAdd(&hist16[i0 >> 1], 1u << ((i0 & 1) << 4));
        atomicAdd(&hist16[i1 >> 1], 1u << ((i1 & 1) << 4));
        atomicAdd(&hist16[i2 >> 1], 1u << ((i2 & 1) << 4));
        atomicAdd(&hist16[i3 >> 1], 1u << ((i3 & 1) << 4));
    }
    for (; e < e1; e += 512) {
        unsigned p = grouped[e];
        unsigned idx = (p >> 24) * 90u + ((p >> 17) & 127u);
        atomicAdd(&hist16[idx >> 1], 1u << ((idx & 1) << 4));
    }
    __syncthreads();
    // pass 2: accumulate + write rinvA, unrolled x4
    e = e0 + tid;
    for (; e + 1536 < e1; e += 2048) {
        unsigned p[4] = {grouped[e], grouped[e + 512], grouped[e + 1024], grouped[e + 1536]};
        float4 xv[4];
#pragma unroll
        for (int k = 0; k < 4; k++) xv[k] = x4[p[k] & 0x1FFFFu];
#pragma unroll
        for (int k = 0; k < 4; k++) {
            unsigned rel = (p[k] >> 17) & 127u, dL = p[k] >> 24;
            unsigned idx = dL * 90u + rel;
            unsigned c = (hist16[idx >> 1] >> ((idx & 1) << 4)) & 0xFFFFu;
            float r = 1.0f / (float)c;
            rinvA[e + k * 512] = r;
            const float* wt = &w[rel * 6];
            float* a = &acc[dL * 6];
            float x0 = xv[k].x * r, x1 = xv[k].y * r, x2 = xv[k].z * r;
            atomicAdd(&a[0], x0 * wt[0]); atomicAdd(&a[1], x0 * wt[1]);
            atomicAdd(&a[2], x1 * wt[2]); atomicAdd(&a[3], x1 * wt[3]);
            atomicAdd(&a[4], x2 * wt[4]); atomicAdd(&a[5], x2 * wt[5]);
        }
    }
    for (; e < e1; e += 512) {
        unsigned p = grouped[e];
        unsigned rel = (p >> 17) & 127u, dL = p >> 24;
        unsigned idx = dL * 90u + rel;
        unsigned c = (hist16[idx >> 1] >> ((idx & 1) << 4)) & 0xFFFFu;
        float r = 1.0f / (float)c;
        rinvA[e] = r;
        float4 xv = x4[p & 0x1FFFFu];
        const float* wt = &w[rel * 6];
        float* a = &acc[dL * 6];
        float x0 = xv.x * r, x1 = xv.y * r, x2 = xv.z * r;
        atomicAdd(&a[0], x0 * wt[0]); atomicAdd(&a[1], x0 * wt[1]);
        atomicAdd(&a[2], x1 * wt[2]); atomicAdd(&a[3], x1 * wt[3]);
        atomicAdd(&a[4], x2 * wt[4]); atomicAdd(&a[5], x2 * wt[5]);
    }
    __syncthreads();
    int d = (b << BSH) + tid;
    if (tid < BNODES && d < N) {
        float4 xv = x4[d];
        float o[6];
#pragma unroll
        for (int j = 0; j < 6; j++)
            o[j] = frelu(acc[tid * 6 + j] + xv.x * root[j] + xv.y * root[6 + j] +
                         xv.z * root[12 + j] + bias[j]);
        h1p[d * 2]     = make_float4(o[0], o[1], o[2], o[3]);
        h1p[d * 2 + 1] = make_float4(o[4], o[5], 0.0f, 0.0f);
    }
}

// ---------- L2 edge: 4 slice-blocks per bucket, partial LDS acc, atomic flush ----------
__launch_bounds__(256)
__global__ void l2_k(const int* __restrict__ bbase, const unsigned* __restrict__ grouped,
                     const float4* __restrict__ h1p, const float* __restrict__ W,
                     float* __restrict__ agg2, int N) {
    __shared__ float w[WSZ];
    __shared__ float acc[BNODES * 3];
    int tid = threadIdx.x;
    for (int i = tid; i < WSZ; i += 256) w[i] = W[i];
    for (int i = tid; i < BNODES * 3; i += 256) acc[i] = 0.0f;
    __syncthreads();
    int b = blockIdx.x >> 2, sl = blockIdx.x & 3;
    int eb0 = bbase[b], len = bbase[b + 1] - eb0;
    int es = eb0 + ((len * sl) >> 2);
    int ee = eb0 + ((len * (sl + 1)) >> 2);
    int e = es + tid;
    for (; e + 768 < ee; e += 1024) {
        unsigned p[4] = {grouped[e], grouped[e + 256], grouped[e + 512], grouped[e + 768]};
        float4 ha[4], hb[4];
#pragma unroll
        for (int k = 0; k < 4; k++) {
            unsigned s = p[k] & 0x1FFFFu;
            ha[k] = h1p[2 * s]; hb[k] = h1p[2 * s + 1];
        }
#pragma unroll
        for (int k = 0; k < 4; k++) {
            unsigned rel = (p[k] >> 17) & 127u, dL = p[k] >> 24;
            const float* wt = &w[rel * 6];
            float* a = &acc[dL * 3];
            atomicAdd(&a[0], ha[k].x * wt[0] + ha[k].y * wt[1]);
            atomicAdd(&a[1], ha[k].z * wt[2] + ha[k].w * wt[3]);
            atomicAdd(&a[2], hb[k].x * wt[4] + hb[k].y * wt[5]);
        }
    }
    for (; e < ee; e += 256) {
        unsigned p = grouped[e];
        unsigned s = p & 0x1FFFFu;
        unsigned rel = (p >> 17) & 127u, dL = p >> 24;
        float4 ha = h1p[2 * s], hb = h1p[2 * s + 1];
        const float* wt = &w[rel * 6];
        float* a = &acc[dL * 3];
        atomicAdd(&a[0], ha.x * wt[0] + ha.y * wt[1]);
        atomicAdd(&a[1], ha.z * wt[2] + ha.w * wt[3]);
        atomicAdd(&a[2], hb.x * wt[4] + hb.y * wt[5]);
    }
    __syncthreads();
    int lim = min(BNODES, N - (b << BSH)) * 3;
    for (int i = tid; i < lim; i += 256) {
        float v = acc[i];
        if (v != 0.0f) unsafeAtomicAdd(&agg2[(size_t)(b << BSH) * 3 + i], v);
    }
}

// ---------- L2 node ----------
__global__ void l2_node_k(const float4* __restrict__ h1p, const float* __restrict__ agg2,
                          const float* __restrict__ root, const float* __restrict__ bias,
                          float4* __restrict__ h2p, int N) {
    int d = blockIdx.x * 256 + threadIdx.x;
    if (d >= N) return;
    float4 ha = h1p[2 * d], hb = h1p[2 * d + 1];
    float hv[6] = {ha.x, ha.y, ha.z, ha.w, hb.x, hb.y};
    float o[3];
#pragma unroll
    for (int j = 0; j < 3; j++) {
        float v = agg2[d * 3 + j] + bias[j];
#pragma unroll
        for (int k = 0; k < 6; k++) v += hv[k] * root[k * 3 + j];
        o[j] = frelu(v);
    }
    h2p[d] = make_float4(o[0], o[1], o[2], 0.0f);
}

// ---------- L3 edge: sliced, reads cached rinvA ----------
__launch_bounds__(256)
__global__ void l3_k(const int* __restrict__ bbase, const unsigned* __restrict__ grouped,
                     const float* __restrict__ rinvA, const float4* __restrict__ h2p,
                     const float* __restrict__ W, float* __restrict__ agg3, int N) {
    __shared__ float w[WSZ];
    __shared__ float acc[BNODES * 6];
    int tid = threadIdx.x;
    for (int i = tid; i < WSZ; i += 256) w[i] = W[i];
    for (int i = tid; i < BNODES * 6; i += 256) acc[i] = 0.0f;
    __syncthreads();
    int b = blockIdx.x >> 2, sl = blockIdx.x & 3;
    int eb0 = bbase[b], len = bbase[b + 1] - eb0;
    int es = eb0 + ((len * sl) >> 2);
    int ee = eb0 + ((len * (sl + 1)) >> 2);
    int e = es + tid;
    for (; e + 768 < ee; e += 1024) {
        unsigned p[4] = {grouped[e], grouped[e + 256], grouped[e + 512], grouped[e + 768]};
        float rv[4] = {rinvA[e], rinvA[e + 256], rinvA[e + 512], rinvA[e + 768]};
        float4 xv[4];
#pragma unroll
        for (int k = 0; k < 4; k++) xv[k] = h2p[p[k] & 0x1FFFFu];
#pragma unroll
        for (int k = 0; k < 4; k++) {
            unsigned rel = (p[k] >> 17) & 127u, dL = p[k] >> 24;
            const float* wt = &w[rel * 6];
            float* a = &acc[dL * 6];
            float x0 = xv[k].x * rv[k], x1 = xv[k].y * rv[k], x2 = xv[k].z * rv[k];
            atomicAdd(&a[0], x0 * wt[0]); atomicAdd(&a[1], x0 * wt[1]);
            atomicAdd(&a[2], x1 * wt[2]); atomicAdd(&a[3], x1 * wt[3]);
            atomicAdd(&a[4], x2 * wt[4]); atomicAdd(&a[5], x2 * wt[5]);
        }
    }
    for (; e < ee; e += 256) {
        unsigned p = grouped[e];
        float r = rinvA[e];
        unsigned rel = (p >> 17) & 127u, dL = p >> 24;
        float4 xv = h2p[p & 0x1FFFFu];
        const float* wt = &w[rel * 6];
        float* a = &acc[dL * 6];
        float x0 = xv.x * r, x1 = xv.y * r, x2 = xv.z * r;
        atomicAdd(&a[0], x0 * wt[0]); atomicAdd(&a[1], x0 * wt[1]);
        atomicAdd(&a[2], x1 * wt[2]); atomicAdd(&a[3], x1 * wt[3]);
        atomicAdd(&a[4], x2 * wt[4]); atomicAdd(&a[5], x2 * wt[5]);
    }
    __syncthreads();
    int lim = min(BNODES, N - (b << BSH)) * 6;
    for (int i = tid; i < lim; i += 256) {
        float v = acc[i];
        if (v != 0.0f) unsafeAtomicAdd(&agg3[(size_t)(b << BSH) * 6 + i], v);
    }
}

// ---------- L3 node + pool partials ----------
__global__ void l3_node_pool_k(const float* __restrict__ agg3, const float4* __restrict__ h2p,
                               const float* __restrict__ root, const float* __restrict__ bias,
                               const int* __restrict__ batch, float* __restrict__ partials, int N) {
    int d = blockIdx.x * 256 + threadIdx.x;
    float v[7] = {0, 0, 0, 0, 0, 0, 0};
    if (d < N && batch[d] == 0) {
        float4 xv = h2p[d];
#pragma unroll
        for (int j = 0; j < 6; j++)
            v[j] = frelu(agg3[d * 6 + j] + xv.x * root[j] + xv.y * root[6 + j] +
                         xv.z * root[12 + j] + bias[j]);
        v[6] = 1.0f;
    }
#pragma unroll
    for (int off = 32; off > 0; off >>= 1) {
#pragma unroll
        for (int k = 0; k < 7; k++) v[k] += __shfl_down(v[k], off);
    }
    __shared__ float redsm[4][8];
    int wv = threadIdx.x >> 6, lane = threadIdx.x & 63;
    if (lane == 0) {
#pragma unroll
        for (int k = 0; k < 7; k++) redsm[wv][k] = v[k];
    }
    __syncthreads();
    if (threadIdx.x == 0) {
#pragma unroll
        for (int k = 0; k < 7; k++)
            partials[(size_t)blockIdx.x * 8 + k] =
                redsm[0][k] + redsm[1][k] + redsm[2][k] + redsm[3][k];
    }
}

// ---------- finalize ----------
__global__ void pool_finalize(const float* __restrict__ partials, int nb,
                              float* __restrict__ out) {
    float v[7] = {0, 0, 0, 0, 0, 0, 0};
    for (int b = threadIdx.x; b < nb; b += blockDim.x) {
#pragma unroll
        for (int k = 0; k < 7; k++) v[k] += partials[(size_t)b * 8 + k];
    }
#pragma unroll
    for (int off = 32; off > 0; off >>= 1) {
#pragma unroll
        for (int k = 0; k < 7; k++) v[k] += __shfl_down(v[k], off);
    }
    __shared__ float sm[16][8];
    int wv = threadIdx.x >> 6, lane = threadIdx.x & 63;
    if (lane == 0) {
#pragma unroll
        for (int k = 0; k < 7; k++) sm[wv][k] = v[k];
    }
    __syncthreads();
    if (threadIdx.x == 0) {
        float t[7] = {0, 0, 0, 0, 0, 0, 0};
        int nw = blockDim.x >> 6;
        for (int q = 0; q < nw; q++) {
#pragma unroll
            for (int k = 0; k < 7; k++) t[k] += sm[q][k];
        }
        float c = t[6] < 1.0f ? 1.0f : t[6];
        float p[6], m = -1e30f;
#pragma unroll
        for (int j = 0; j < 6; j++) { p[j] = t[j] / c; m = fmaxf(m, p[j]); }
        float s = 0.0f;
#pragma unroll
        for (int j = 0; j < 6; j++) s += expf(p[j] - m);
        float lse = m + logf(s);
#pragma unroll
        for (int j = 0; j < 6; j++) out[j] = p[j] - lse;
    }
}

extern "C" void kernel_launch(void* const* d_in, const int* in_sizes, int n_in,
                              void* d_out, int out_size, void* d_ws, size_t ws_size,
                              hipStream_t stream) {
    const float* x     = (const float*)d_in[0];
    const int*   ei    = (const int*)d_in[1];
    const int*   batch = (const int*)d_in[2];
    const int*   etype = (const int*)d_in[3];
    const float* W1    = (const float*)d_in[4];
    const float* root1 = (const float*)d_in[5];
    const float* b1    = (const float*)d_in[6];
    const float* W2    = (const float*)d_in[7];
    const float* root2 = (const float*)d_in[8];
    const float* b2    = (const float*)d_in[9];
    const float* W3    = (const float*)d_in[10];
    const float* root3 = (const float*)d_in[11];
    const float* b3    = (const float*)d_in[12];

    const int N = in_sizes[0] / 3;
    const int E = in_sizes[1] / 2;
    const int* src = ei;
    const int* dst = ei + E;

    char* ws = (char*)d_ws;
    size_t off = 0;
    auto alloc = [&](size_t bytes) -> void* {
        void* p = ws + off;
        off += (bytes + 255) & ~(size_t)255;
        return p;
    };
    // zero region: bhist + agg2 + agg3
    int*      bhist   = (int*)     alloc(NBINS * sizeof(int));
    float*    agg2    = (float*)   alloc((size_t)N * 3 * sizeof(float));
    float*    agg3    = (float*)   alloc((size_t)N * 6 * sizeof(float));
    size_t zero_bytes = off;
    int*      bbase   = (int*)     alloc((NBINS + 1) * sizeof(int));
    int*      gcursor = (int*)     alloc(NBINS * sizeof(int));
    unsigned* grouped = (unsigned*)alloc((size_t)E * sizeof(unsigned));  // 25.6 MB
    float*    rinvA   = (float*)   alloc((size_t)E * sizeof(float));     // 25.6 MB
    float4*   x4      = (float4*)  alloc((size_t)N * sizeof(float4));
    float4*   h1p     = (float4*)  alloc((size_t)N * 2 * sizeof(float4));
    float4*   h2p     = (float4*)  alloc((size_t)N * sizeof(float4));
    const int NBUCK = (N + BNODES - 1) >> BSH;                           // 782
    const int gN    = (N + 255) / 256;                                   // 391
    float*    partials = (float*)  alloc((size_t)gN * 8 * sizeof(float));

    hipMemsetAsync(d_ws, 0, zero_bytes, stream);

    const int gH = (E + HCH - 1) / HCH;
    const int gG = (E + GCH - 1) / GCH;

    padx_k<<<gN, 256, 0, stream>>>(x, x4, N);
    bucket_hist_k<<<gH, 512, 0, stream>>>(dst, bhist, E);
    bucket_scan_k<<<1, 64, 0, stream>>>(bhist, bbase, gcursor);
    group_k<<<gG, 512, 0, stream>>>(src, dst, etype, gcursor, grouped, E);

    l1_k<<<NBUCK, 512, 0, stream>>>(bbase, grouped, x4, W1, root1, b1, rinvA, h1p, N);
    l2_k<<<NBUCK * 4, 256, 0, stream>>>(bbase, grouped, h1p, W2, agg2, N);
    l2_node_k<<<gN, 256, 0, stream>>>(h1p, agg2, root2, b2, h2p, N);
    l3_k<<<NBUCK * 4, 256, 0, stream>>>(bbase, grouped, rinvA, h2p, W3, agg3, N);
    l3_node_pool_k<<<gN, 256, 0, stream>>>(agg3, h2p, root3, b3, batch, partials, N);
    pool_finalize<<<1, 1024, 0, stream>>>(partials, gN, (float*)d_out);
}

// Round 6
// 425.198 us; speedup vs baseline: 12.1132x; 1.8875x over previous
//
#include <hip/hip_runtime.h>

// RGCN: bucket (dst>>6) -> LDS-staged grouping -> in-place per-bucket counting
// sort (globally dst-sorted edges + rowptr + cached rinv), then wave-per-dst
// register-accumulation gathers (no fp32 atomics, no per-layer histograms).
// R5 failed nondeterministically: 84 MB ws footprint (likely overflow) + 64KB-
// exact LDS in sortb_k. R6: in-place sort (-25.6 MB, total ~59 MB), BSH=6
// (sortb LDS 32.8KB), guarded stage writes, float4-packed W in LDS.

#define NREL   90
#define BSH    6
#define BNODES 64        // nodes per bucket
#define NBINS  2048      // padded bucket count (N <= 131072)
#define GCH    4096      // edges per grouping block
#define HCH    16384     // edges per hist block
#define STAGE  5120      // bucket capacity; mean 4096, sigma ~64 -> +16 sigma

__device__ __forceinline__ float frelu(float v) { return v > 0.0f ? v : 0.0f; }

// ---------- K0: pad x[N,3] -> float4 ----------
__global__ void padx_k(const float* __restrict__ x, float4* __restrict__ x4, int N) {
    int i = blockIdx.x * 256 + threadIdx.x;
    if (i < N) x4[i] = make_float4(x[3 * i], x[3 * i + 1], x[3 * i + 2], 0.0f);
}

// ---------- K1: global bucket histogram ----------
__launch_bounds__(512)
__global__ void bucket_hist_k(const int* __restrict__ dst, int* __restrict__ bhist, int E) {
    __shared__ int h[NBINS];
    int tid = threadIdx.x;
    for (int i = tid; i < NBINS; i += 512) h[i] = 0;
    __syncthreads();
    int e0 = blockIdx.x * HCH;
    int e1 = min(e0 + HCH, E);
    for (int e = e0 + tid; e < e1; e += 512) atomicAdd(&h[dst[e] >> BSH], 1);
    __syncthreads();
    for (int i = tid; i < NBINS; i += 512)
        if (h[i]) atomicAdd(&bhist[i], h[i]);
}

// ---------- K2: exclusive scan of 2048 bins (one wave, 32 bins/lane) ----------
__global__ void bucket_scan_k(const int* __restrict__ bhist, int* __restrict__ bbase,
                              int* __restrict__ gcursor) {
    int lane = threadIdx.x;  // 64
    int loc[32];
    int s = 0;
    int b0 = lane * 32;
#pragma unroll
    for (int k = 0; k < 32; k++) { loc[k] = bhist[b0 + k]; s += loc[k]; }
    int inc = s;
#pragma unroll
    for (int off = 1; off < 64; off <<= 1) {
        int u = __shfl_up(inc, off);
        if (lane >= off) inc += u;
    }
    int run = inc - s;
#pragma unroll
    for (int k = 0; k < 32; k++) {
        bbase[b0 + k] = run;
        gcursor[b0 + k] = run;
        run += loc[k];
    }
}

// ---------- K3: LDS-staged grouping; record = src | rel<<17 | dstLocal<<24 ----------
__launch_bounds__(512)
__global__ void group_k(const int* __restrict__ src, const int* __restrict__ dst,
                        const int* __restrict__ et, int* __restrict__ gcursor,
                        unsigned* __restrict__ edges, int E) {
    __shared__ int s_hist[NBINS];
    __shared__ int s_cur[NBINS];
    __shared__ int s_gb2[NBINS];
    __shared__ unsigned s_pack[GCH];
    __shared__ unsigned short s_bkt[GCH];
    int tid = threadIdx.x;
    for (int i = tid; i < NBINS; i += 512) s_hist[i] = 0;
    __syncthreads();
    int e0 = blockIdx.x * GCH;
    int cnt = min(GCH, E - e0);
    for (int i = tid; i < cnt; i += 512) atomicAdd(&s_hist[dst[e0 + i] >> BSH], 1);
    __syncthreads();
    if (tid < 64) {   // exclusive scan, 32 bins/lane
        int loc[32];
        int s = 0;
        int b0 = tid * 32;
#pragma unroll
        for (int k = 0; k < 32; k++) { loc[k] = s_hist[b0 + k]; s += loc[k]; }
        int inc = s;
#pragma unroll
        for (int off = 1; off < 64; off <<= 1) {
            int u = __shfl_up(inc, off);
            if (tid >= off) inc += u;
        }
        int run = inc - s;
#pragma unroll
        for (int k = 0; k < 32; k++) { s_cur[b0 + k] = run; run += loc[k]; }
    }
    __syncthreads();
    for (int q = tid; q < NBINS; q += 512) {
        int c = s_hist[q];
        int gb = c ? atomicAdd(&gcursor[q], c) : 0;
        s_gb2[q] = gb - s_cur[q];
    }
    __syncthreads();
    for (int q = tid; q < cnt; q += 512) {
        int e = e0 + q;
        int d = dst[e];
        int b = d >> BSH;
        int p = atomicAdd(&s_cur[b], 1);
        if (p < GCH) {
            s_pack[p] = (unsigned)src[e] | ((unsigned)et[e] << 17) |
                        ((unsigned)(d & (BNODES - 1)) << 24);
            s_bkt[p] = (unsigned short)b;
        }
    }
    __syncthreads();
    for (int q = tid; q < cnt; q += 512) {
        int b = s_bkt[q];
        edges[s_gb2[b] + q] = s_pack[q];
    }
}

// ---------- K4: in-place per-bucket counting sort by dstLocal + rowptr + rinvA ----------
__launch_bounds__(512)
__global__ void sortb_k(const int* __restrict__ bbase, unsigned* __restrict__ edges,
                        float* __restrict__ rinvA, int* __restrict__ rowptr, int N) {
    __shared__ unsigned stage[STAGE];          // 20480 B
    __shared__ unsigned hist16[BNODES * 45];   // 11520 B, u16-packed (dL,rel) counts
    __shared__ int hh[BNODES], cur[BNODES], base_[BNODES];  // 768 B
    int tid = threadIdx.x, b = blockIdx.x;
    for (int i = tid; i < BNODES * 45; i += 512) hist16[i] = 0u;
    __syncthreads();
    int e0 = bbase[b], e1 = bbase[b + 1], cnt = e1 - e0;
    for (int e = e0 + tid; e < e1; e += 512) {
        unsigned p = edges[e];
        unsigned idx = (p >> 24) * 90u + ((p >> 17) & 127u);
        atomicAdd(&hist16[idx >> 1], 1u << ((idx & 1) << 4));
    }
    __syncthreads();
    if (tid < BNODES) {   // per-dst totals (row dL = hist16[dL*45 .. dL*45+44])
        unsigned s = 0;
        for (int k = 0; k < 45; k++) {
            unsigned wv = hist16[tid * 45 + k];
            s += (wv & 0xFFFFu) + (wv >> 16);
        }
        hh[tid] = (int)s;
    }
    __syncthreads();
    if (tid < 64) {       // exclusive scan of 64 bins, 1/lane
        int c = hh[tid];
        int inc = c;
#pragma unroll
        for (int off = 1; off < 64; off <<= 1) {
            int u = __shfl_up(inc, off);
            if (tid >= off) inc += u;
        }
        int run = inc - c;
        base_[tid] = run;
        cur[tid] = run;
    }
    __syncthreads();
    if (tid < BNODES) {
        int d = (b << BSH) + tid;
        if (d <= N) rowptr[d] = e0 + base_[tid];
    }
    for (int e = e0 + tid; e < e1; e += 512) {    // all reads of edges[] done here
        unsigned p = edges[e];
        int pos = atomicAdd(&cur[p >> 24], 1);
        if (pos < STAGE) stage[pos] = p;
    }
    __syncthreads();
    int m = cnt < STAGE ? cnt : STAGE;
    for (int i = tid; i < m; i += 512) {          // writes after barrier: in-place safe
        unsigned p = stage[i];
        unsigned idx = (p >> 24) * 90u + ((p >> 17) & 127u);
        unsigned c = (hist16[idx >> 1] >> ((idx & 1) << 4)) & 0xFFFFu;
        edges[e0 + i] = p;
        rinvA[e0 + i] = 1.0f / (float)c;
    }
}

// ---------- L1: wave per dst, register acc, fused node ----------
__launch_bounds__(256)
__global__ void l1_g(const int* __restrict__ rowptr, const unsigned* __restrict__ sorted,
                     const float* __restrict__ rinvA, const float4* __restrict__ x4,
                     const float* __restrict__ W, const float* __restrict__ root,
                     const float* __restrict__ bias, float4* __restrict__ h1p, int N) {
    __shared__ float4 w4[NREL * 2];
    for (int i = threadIdx.x; i < NREL * 2; i += 256) {
        int r = i >> 1;
        w4[i] = (i & 1) ? make_float4(W[r * 6 + 4], W[r * 6 + 5], 0.f, 0.f)
                        : make_float4(W[r * 6], W[r * 6 + 1], W[r * 6 + 2], W[r * 6 + 3]);
    }
    __syncthreads();
    int wv = threadIdx.x >> 6, lane = threadIdx.x & 63;
    int d = blockIdx.x * 4 + wv;
    if (d >= N) return;
    int beg = rowptr[d], end = rowptr[d + 1];
    float a0 = 0, a1 = 0, a2 = 0, a3 = 0, a4 = 0, a5 = 0;
    for (int i = beg + lane; i < end; i += 64) {
        unsigned p = sorted[i];
        float r = rinvA[i];
        float4 xv = x4[p & 0x1FFFFu];
        unsigned rel2 = ((p >> 17) & 127u) * 2u;
        float4 wa = w4[rel2], wb = w4[rel2 + 1];
        float x0 = xv.x * r, x1 = xv.y * r, x2 = xv.z * r;
        a0 += x0 * wa.x; a1 += x0 * wa.y;
        a2 += x1 * wa.z; a3 += x1 * wa.w;
        a4 += x2 * wb.x; a5 += x2 * wb.y;
    }
#pragma unroll
    for (int off = 32; off > 0; off >>= 1) {
        a0 += __shfl_down(a0, off); a1 += __shfl_down(a1, off); a2 += __shfl_down(a2, off);
        a3 += __shfl_down(a3, off); a4 += __shfl_down(a4, off); a5 += __shfl_down(a5, off);
    }
    if (lane == 0) {
        float4 xv = x4[d];
        float o[6] = {a0, a1, a2, a3, a4, a5};
#pragma unroll
        for (int j = 0; j < 6; j++)
            o[j] = frelu(o[j] + xv.x * root[j] + xv.y * root[6 + j] + xv.z * root[12 + j] + bias[j]);
        h1p[d * 2]     = make_float4(o[0], o[1], o[2], o[3]);
        h1p[d * 2 + 1] = make_float4(o[4], o[5], 0.0f, 0.0f);
    }
}

// ---------- L2: wave per dst, sum aggr, fused node ----------
__launch_bounds__(256)
__global__ void l2_g(const int* __restrict__ rowptr, const unsigned* __restrict__ sorted,
                     const float4* __restrict__ h1p, const float* __restrict__ W,
                     const float* __restrict__ root, const float* __restrict__ bias,
                     float4* __restrict__ h2p, int N) {
    __shared__ float4 w4[NREL * 2];
    for (int i = threadIdx.x; i < NREL * 2; i += 256) {
        int r = i >> 1;
        w4[i] = (i & 1) ? make_float4(W[r * 6 + 4], W[r * 6 + 5], 0.f, 0.f)
                        : make_float4(W[r * 6], W[r * 6 + 1], W[r * 6 + 2], W[r * 6 + 3]);
    }
    __syncthreads();
    int wv = threadIdx.x >> 6, lane = threadIdx.x & 63;
    int d = blockIdx.x * 4 + wv;
    if (d >= N) return;
    int beg = rowptr[d], end = rowptr[d + 1];
    float a0 = 0, a1 = 0, a2 = 0;
    for (int i = beg + lane; i < end; i += 64) {
        unsigned p = sorted[i];
        unsigned s = p & 0x1FFFFu;
        float4 ha = h1p[2 * s], hb = h1p[2 * s + 1];
        unsigned rel2 = ((p >> 17) & 127u) * 2u;
        float4 wa = w4[rel2], wb = w4[rel2 + 1];
        a0 += ha.x * wa.x + ha.y * wa.y;
        a1 += ha.z * wa.z + ha.w * wa.w;
        a2 += hb.x * wb.x + hb.y * wb.y;
    }
#pragma unroll
    for (int off = 32; off > 0; off >>= 1) {
        a0 += __shfl_down(a0, off); a1 += __shfl_down(a1, off); a2 += __shfl_down(a2, off);
    }
    if (lane == 0) {
        float4 ha = h1p[2 * d], hb = h1p[2 * d + 1];
        float hv[6] = {ha.x, ha.y, ha.z, ha.w, hb.x, hb.y};
        float o[3] = {a0, a1, a2};
#pragma unroll
        for (int j = 0; j < 3; j++) {
            float v = o[j] + bias[j];
#pragma unroll
            for (int k = 0; k < 6; k++) v += hv[k] * root[k * 3 + j];
            o[j] = frelu(v);
        }
        h2p[d] = make_float4(o[0], o[1], o[2], 0.0f);
    }
}

// ---------- L3: wave per dst, mean via rinvA, fused node + pool partials ----------
__launch_bounds__(256)
__global__ void l3_g(const int* __restrict__ rowptr, const unsigned* __restrict__ sorted,
                     const float* __restrict__ rinvA, const float4* __restrict__ h2p,
                     const float* __restrict__ W, const float* __restrict__ root,
                     const float* __restrict__ bias, const int* __restrict__ batch,
                     float* __restrict__ partials, int N) {
    __shared__ float4 w4[NREL * 2];
    __shared__ float redsm[4][8];
    for (int i = threadIdx.x; i < NREL * 2; i += 256) {
        int r = i >> 1;
        w4[i] = (i & 1) ? make_float4(W[r * 6 + 4], W[r * 6 + 5], 0.f, 0.f)
                        : make_float4(W[r * 6], W[r * 6 + 1], W[r * 6 + 2], W[r * 6 + 3]);
    }
    __syncthreads();
    int wv = threadIdx.x >> 6, lane = threadIdx.x & 63;
    int d = blockIdx.x * 4 + wv;
    float a0 = 0, a1 = 0, a2 = 0, a3 = 0, a4 = 0, a5 = 0;
    if (d < N) {
        int beg = rowptr[d], end = rowptr[d + 1];
        for (int i = beg + lane; i < end; i += 64) {
            unsigned p = sorted[i];
            float r = rinvA[i];
            float4 xv = h2p[p & 0x1FFFFu];
            unsigned rel2 = ((p >> 17) & 127u) * 2u;
            float4 wa = w4[rel2], wb = w4[rel2 + 1];
            float x0 = xv.x * r, x1 = xv.y * r, x2 = xv.z * r;
            a0 += x0 * wa.x; a1 += x0 * wa.y;
            a2 += x1 * wa.z; a3 += x1 * wa.w;
            a4 += x2 * wb.x; a5 += x2 * wb.y;
        }
    }
#pragma unroll
    for (int off = 32; off > 0; off >>= 1) {
        a0 += __shfl_down(a0, off); a1 += __shfl_down(a1, off); a2 += __shfl_down(a2, off);
        a3 += __shfl_down(a3, off); a4 += __shfl_down(a4, off); a5 += __shfl_down(a5, off);
    }
    if (lane == 0) {
        float v[7] = {0, 0, 0, 0, 0, 0, 0};
        if (d < N && batch[d] == 0) {
            float4 xv = h2p[d];
            float o[6] = {a0, a1, a2, a3, a4, a5};
#pragma unroll
            for (int j = 0; j < 6; j++)
                v[j] = frelu(o[j] + xv.x * root[j] + xv.y * root[6 + j] +
                             xv.z * root[12 + j] + bias[j]);
            v[6] = 1.0f;
        }
#pragma unroll
        for (int k = 0; k < 7; k++) redsm[wv][k] = v[k];
    }
    __syncthreads();
    if (threadIdx.x == 0) {
#pragma unroll
        for (int k = 0; k < 7; k++)
            partials[(size_t)blockIdx.x * 8 + k] =
                redsm[0][k] + redsm[1][k] + redsm[2][k] + redsm[3][k];
    }
}

// ---------- finalize ----------
__global__ void pool_finalize(const float* __restrict__ partials, int nb,
                              float* __restrict__ out) {
    float v[7] = {0, 0, 0, 0, 0, 0, 0};
    for (int b = threadIdx.x; b < nb; b += blockDim.x) {
#pragma unroll
        for (int k = 0; k < 7; k++) v[k] += partials[(size_t)b * 8 + k];
    }
#pragma unroll
    for (int off = 32; off > 0; off >>= 1) {
#pragma unroll
        for (int k = 0; k < 7; k++) v[k] += __shfl_down(v[k], off);
    }
    __shared__ float sm[16][8];
    int wv = threadIdx.x >> 6, lane = threadIdx.x & 63;
    if (lane == 0) {
#pragma unroll
        for (int k = 0; k < 7; k++) sm[wv][k] = v[k];
    }
    __syncthreads();
    if (threadIdx.x == 0) {
        float t[7] = {0, 0, 0, 0, 0, 0, 0};
        int nw = blockDim.x >> 6;
        for (int q = 0; q < nw; q++) {
#pragma unroll
            for (int k = 0; k < 7; k++) t[k] += sm[q][k];
        }
        float c = t[6] < 1.0f ? 1.0f : t[6];
        float p[6], m = -1e30f;
#pragma unroll
        for (int j = 0; j < 6; j++) { p[j] = t[j] / c; m = fmaxf(m, p[j]); }
        float s = 0.0f;
#pragma unroll
        for (int j = 0; j < 6; j++) s += expf(p[j] - m);
        float lse = m + logf(s);
#pragma unroll
        for (int j = 0; j < 6; j++) out[j] = p[j] - lse;
    }
}

extern "C" void kernel_launch(void* const* d_in, const int* in_sizes, int n_in,
                              void* d_out, int out_size, void* d_ws, size_t ws_size,
                              hipStream_t stream) {
    const float* x     = (const float*)d_in[0];
    const int*   ei    = (const int*)d_in[1];
    const int*   batch = (const int*)d_in[2];
    const int*   etype = (const int*)d_in[3];
    const float* W1    = (const float*)d_in[4];
    const float* root1 = (const float*)d_in[5];
    const float* b1    = (const float*)d_in[6];
    const float* W2    = (const float*)d_in[7];
    const float* root2 = (const float*)d_in[8];
    const float* b2    = (const float*)d_in[9];
    const float* W3    = (const float*)d_in[10];
    const float* root3 = (const float*)d_in[11];
    const float* b3    = (const float*)d_in[12];

    const int N = in_sizes[0] / 3;
    const int E = in_sizes[1] / 2;
    const int* src = ei;
    const int* dst = ei + E;

    char* ws = (char*)d_ws;
    size_t off = 0;
    auto alloc = [&](size_t bytes) -> void* {
        void* p = ws + off;
        off += (bytes + 255) & ~(size_t)255;
        return p;
    };
    int*      bhist   = (int*)     alloc(NBINS * sizeof(int));           // zeroed
    size_t zero_bytes = off;
    int*      bbase   = (int*)     alloc((NBINS + 1) * sizeof(int));
    int*      gcursor = (int*)     alloc(NBINS * sizeof(int));
    unsigned* edges   = (unsigned*)alloc((size_t)E * sizeof(unsigned));  // 25.6 MB (grouped, then sorted in-place)
    float*    rinvA   = (float*)   alloc((size_t)E * sizeof(float));     // 25.6 MB
    int*      rowptr  = (int*)     alloc((size_t)(N + 1) * sizeof(int));
    float4*   x4      = (float4*)  alloc((size_t)N * sizeof(float4));
    float4*   h1p     = (float4*)  alloc((size_t)N * 2 * sizeof(float4));
    float4*   h2p     = (float4*)  alloc((size_t)N * sizeof(float4));
    const int NBUCK = (N + BNODES - 1) >> BSH;                           // 1563
    const int gW    = (N + 3) / 4;                                       // 25000
    float*    partials = (float*)  alloc((size_t)gW * 8 * sizeof(float));
    // total ~59 MB

    hipMemsetAsync(d_ws, 0, zero_bytes, stream);

    const int gN = (N + 255) / 256;
    const int gH = (E + HCH - 1) / HCH;
    const int gG = (E + GCH - 1) / GCH;

    padx_k<<<gN, 256, 0, stream>>>(x, x4, N);
    bucket_hist_k<<<gH, 512, 0, stream>>>(dst, bhist, E);
    bucket_scan_k<<<1, 64, 0, stream>>>(bhist, bbase, gcursor);
    group_k<<<gG, 512, 0, stream>>>(src, dst, etype, gcursor, edges, E);
    sortb_k<<<NBUCK, 512, 0, stream>>>(bbase, edges, rinvA, rowptr, N);

    l1_g<<<gW, 256, 0, stream>>>(rowptr, edges, rinvA, x4, W1, root1, b1, h1p, N);
    l2_g<<<gW, 256, 0, stream>>>(rowptr, edges, h1p, W2, root2, b2, h2p, N);
    l3_g<<<gW, 256, 0, stream>>>(rowptr, edges, rinvA, h2p, W3, root3, b3, batch, partials, N);
    pool_finalize<<<1, 1024, 0, stream>>>(partials, gW, (float*)d_out);
}

// Round 7
// 407.910 us; speedup vs baseline: 12.6266x; 1.0424x over previous
//
#include <hip/hip_runtime.h>

// RGCN: bucket (dst>>7) -> LDS-staged grouping (8192-edge chunks, ~10-edge
// write bursts) -> in-place per-bucket counting sort (dst-sorted edges,
// rowptr, per-edge u16 (dst,rel)-count) -> wave-per-dst register gathers.
// R6 postmortem: group_k had 3.7x write amplification (2.6-edge bursts with
// 1563 buckets x 4096-edge chunks). R7: 782 buckets x 8192-edge chunks,
// rinv f32 -> cnt u16 (halves norm traffic), layers use v_rcp.

#define NREL   90
#define BSH    7
#define BNODES 128       // nodes per bucket
#define NBINS  1024      // padded bucket count (N <= 131072)
#define GCH    8192      // edges per grouping block
#define HCH    16384     // edges per hist block
#define STAGE  9216      // bucket capacity; mean 8192, sigma ~90 -> +11 sigma

__device__ __forceinline__ float frelu(float v) { return v > 0.0f ? v : 0.0f; }

// ---------- K0: pad x[N,3] -> float4 ----------
__global__ void padx_k(const float* __restrict__ x, float4* __restrict__ x4, int N) {
    int i = blockIdx.x * 256 + threadIdx.x;
    if (i < N) x4[i] = make_float4(x[3 * i], x[3 * i + 1], x[3 * i + 2], 0.0f);
}

// ---------- K1: global bucket histogram ----------
__launch_bounds__(512)
__global__ void bucket_hist_k(const int* __restrict__ dst, int* __restrict__ bhist, int E) {
    __shared__ int h[NBINS];
    int tid = threadIdx.x;
    for (int i = tid; i < NBINS; i += 512) h[i] = 0;
    __syncthreads();
    int e0 = blockIdx.x * HCH;
    int e1 = min(e0 + HCH, E);
    for (int e = e0 + tid; e < e1; e += 512) atomicAdd(&h[dst[e] >> BSH], 1);
    __syncthreads();
    for (int i = tid; i < NBINS; i += 512)
        if (h[i]) atomicAdd(&bhist[i], h[i]);
}

// ---------- K2: exclusive scan of 1024 bins (one wave, 16 bins/lane) ----------
__global__ void bucket_scan_k(const int* __restrict__ bhist, int* __restrict__ bbase,
                              int* __restrict__ gcursor) {
    int lane = threadIdx.x;  // 64
    int loc[16];
    int s = 0;
    int b0 = lane * 16;
#pragma unroll
    for (int k = 0; k < 16; k++) { loc[k] = bhist[b0 + k]; s += loc[k]; }
    int inc = s;
#pragma unroll
    for (int off = 1; off < 64; off <<= 1) {
        int u = __shfl_up(inc, off);
        if (lane >= off) inc += u;
    }
    int run = inc - s;
#pragma unroll
    for (int k = 0; k < 16; k++) {
        bbase[b0 + k] = run;
        gcursor[b0 + k] = run;
        run += loc[k];
    }
}

// ---------- K3: LDS-staged grouping; record = src | rel<<17 | dstLocal<<24 ----------
__launch_bounds__(512)
__global__ void group_k(const int* __restrict__ src, const int* __restrict__ dst,
                        const int* __restrict__ et, int* __restrict__ gcursor,
                        unsigned* __restrict__ edges, int E) {
    __shared__ int s_hist[NBINS];                 // 4 KB
    __shared__ int s_cur[NBINS];                  // 4 KB
    __shared__ int s_gb2[NBINS];                  // 4 KB
    __shared__ unsigned s_pack[GCH];              // 32 KB
    __shared__ unsigned short s_bkt[GCH];         // 16 KB  -> 60 KB total
    int tid = threadIdx.x;
    for (int i = tid; i < NBINS; i += 512) s_hist[i] = 0;
    __syncthreads();
    int e0 = blockIdx.x * GCH;
    int cnt = min(GCH, E - e0);
    for (int i = tid; i < cnt; i += 512) atomicAdd(&s_hist[dst[e0 + i] >> BSH], 1);
    __syncthreads();
    if (tid < 64) {   // exclusive scan, 16 bins/lane
        int loc[16];
        int s = 0;
        int b0 = tid * 16;
#pragma unroll
        for (int k = 0; k < 16; k++) { loc[k] = s_hist[b0 + k]; s += loc[k]; }
        int inc = s;
#pragma unroll
        for (int off = 1; off < 64; off <<= 1) {
            int u = __shfl_up(inc, off);
            if (tid >= off) inc += u;
        }
        int run = inc - s;
#pragma unroll
        for (int k = 0; k < 16; k++) { s_cur[b0 + k] = run; run += loc[k]; }
    }
    __syncthreads();
    for (int q = tid; q < NBINS; q += 512) {
        int c = s_hist[q];
        int gb = c ? atomicAdd(&gcursor[q], c) : 0;
        s_gb2[q] = gb - s_cur[q];
    }
    __syncthreads();
    for (int q = tid; q < cnt; q += 512) {
        int e = e0 + q;
        int d = dst[e];
        int b = d >> BSH;
        int p = atomicAdd(&s_cur[b], 1);
        if (p < GCH) {
            s_pack[p] = (unsigned)src[e] | ((unsigned)et[e] << 17) |
                        ((unsigned)(d & (BNODES - 1)) << 24);
            s_bkt[p] = (unsigned short)b;
        }
    }
    __syncthreads();
    for (int q = tid; q < cnt; q += 512) {    // bucket-sorted stage -> ~10-edge bursts
        int b = s_bkt[q];
        edges[s_gb2[b] + q] = s_pack[q];
    }
}

// ---------- K4: in-place per-bucket counting sort + rowptr + cnt16 ----------
__launch_bounds__(512)
__global__ void sortb_k(const int* __restrict__ bbase, unsigned* __restrict__ edges,
                        unsigned short* __restrict__ cntA, int* __restrict__ rowptr, int N) {
    __shared__ unsigned stage[STAGE];          // 36864 B
    __shared__ unsigned hist16[BNODES * 45];   // 23040 B, u16-packed (dL,rel) counts
    __shared__ int hh[BNODES], cur[BNODES], base_[BNODES];  // 1536 B -> 61440 total
    int tid = threadIdx.x, b = blockIdx.x;
    for (int i = tid; i < BNODES * 45; i += 512) hist16[i] = 0u;
    __syncthreads();
    int e0 = bbase[b], e1 = bbase[b + 1], cnt = e1 - e0;
    for (int e = e0 + tid; e < e1; e += 512) {
        unsigned p = edges[e];
        unsigned idx = (p >> 24) * 90u + ((p >> 17) & 127u);
        atomicAdd(&hist16[idx >> 1], 1u << ((idx & 1) << 4));
    }
    __syncthreads();
    if (tid < BNODES) {   // per-dst totals (row dL = hist16[dL*45 .. dL*45+44])
        unsigned s = 0;
        for (int k = 0; k < 45; k++) {
            unsigned wv = hist16[tid * 45 + k];
            s += (wv & 0xFFFFu) + (wv >> 16);
        }
        hh[tid] = (int)s;
    }
    __syncthreads();
    if (tid < 64) {       // exclusive scan of 128 bins, 2/lane
        int c0 = hh[2 * tid], c1 = hh[2 * tid + 1];
        int s = c0 + c1;
        int inc = s;
#pragma unroll
        for (int off = 1; off < 64; off <<= 1) {
            int u = __shfl_up(inc, off);
            if (tid >= off) inc += u;
        }
        int run = inc - s;
        base_[2 * tid] = run;         cur[2 * tid] = run;
        base_[2 * tid + 1] = run + c0; cur[2 * tid + 1] = run + c0;
    }
    __syncthreads();
    if (tid < BNODES) {
        int d = (b << BSH) + tid;
        if (d <= N) rowptr[d] = e0 + base_[tid];
    }
    for (int e = e0 + tid; e < e1; e += 512) {    // all reads of edges[] before barrier
        unsigned p = edges[e];
        int pos = atomicAdd(&cur[p >> 24], 1);
        if (pos < STAGE) stage[pos] = p;
    }
    __syncthreads();
    int m = cnt < STAGE ? cnt : STAGE;
    for (int i = tid; i < m; i += 512) {          // writes after barrier: in-place safe
        unsigned p = stage[i];
        unsigned idx = (p >> 24) * 90u + ((p >> 17) & 127u);
        unsigned c = (hist16[idx >> 1] >> ((idx & 1) << 4)) & 0xFFFFu;
        edges[e0 + i] = p;
        cntA[e0 + i] = (unsigned short)c;
    }
}

// ---------- L1: wave per dst, register acc, fused node ----------
__launch_bounds__(256)
__global__ void l1_g(const int* __restrict__ rowptr, const unsigned* __restrict__ sorted,
                     const unsigned short* __restrict__ cntA, const float4* __restrict__ x4,
                     const float* __restrict__ W, const float* __restrict__ root,
                     const float* __restrict__ bias, float4* __restrict__ h1p, int N) {
    __shared__ float4 w4[NREL * 2];
    for (int i = threadIdx.x; i < NREL * 2; i += 256) {
        int r = i >> 1;
        w4[i] = (i & 1) ? make_float4(W[r * 6 + 4], W[r * 6 + 5], 0.f, 0.f)
                        : make_float4(W[r * 6], W[r * 6 + 1], W[r * 6 + 2], W[r * 6 + 3]);
    }
    __syncthreads();
    int wv = threadIdx.x >> 6, lane = threadIdx.x & 63;
    int d = blockIdx.x * 4 + wv;
    if (d >= N) return;
    int beg = rowptr[d], end = rowptr[d + 1];
    float a0 = 0, a1 = 0, a2 = 0, a3 = 0, a4 = 0, a5 = 0;
    for (int i = beg + lane; i < end; i += 64) {
        unsigned p = sorted[i];
        float r = __builtin_amdgcn_rcpf((float)cntA[i]);
        float4 xv = x4[p & 0x1FFFFu];
        unsigned rel2 = ((p >> 17) & 127u) * 2u;
        float4 wa = w4[rel2], wb = w4[rel2 + 1];
        float x0 = xv.x * r, x1 = xv.y * r, x2 = xv.z * r;
        a0 += x0 * wa.x; a1 += x0 * wa.y;
        a2 += x1 * wa.z; a3 += x1 * wa.w;
        a4 += x2 * wb.x; a5 += x2 * wb.y;
    }
#pragma unroll
    for (int off = 32; off > 0; off >>= 1) {
        a0 += __shfl_down(a0, off); a1 += __shfl_down(a1, off); a2 += __shfl_down(a2, off);
        a3 += __shfl_down(a3, off); a4 += __shfl_down(a4, off); a5 += __shfl_down(a5, off);
    }
    if (lane == 0) {
        float4 xv = x4[d];
        float o[6] = {a0, a1, a2, a3, a4, a5};
#pragma unroll
        for (int j = 0; j < 6; j++)
            o[j] = frelu(o[j] + xv.x * root[j] + xv.y * root[6 + j] + xv.z * root[12 + j] + bias[j]);
        h1p[d * 2]     = make_float4(o[0], o[1], o[2], o[3]);
        h1p[d * 2 + 1] = make_float4(o[4], o[5], 0.0f, 0.0f);
    }
}

// ---------- L2: wave per dst, sum aggr, fused node ----------
__launch_bounds__(256)
__global__ void l2_g(const int* __restrict__ rowptr, const unsigned* __restrict__ sorted,
                     const float4* __restrict__ h1p, const float* __restrict__ W,
                     const float* __restrict__ root, const float* __restrict__ bias,
                     float4* __restrict__ h2p, int N) {
    __shared__ float4 w4[NREL * 2];
    for (int i = threadIdx.x; i < NREL * 2; i += 256) {
        int r = i >> 1;
        w4[i] = (i & 1) ? make_float4(W[r * 6 + 4], W[r * 6 + 5], 0.f, 0.f)
                        : make_float4(W[r * 6], W[r * 6 + 1], W[r * 6 + 2], W[r * 6 + 3]);
    }
    __syncthreads();
    int wv = threadIdx.x >> 6, lane = threadIdx.x & 63;
    int d = blockIdx.x * 4 + wv;
    if (d >= N) return;
    int beg = rowptr[d], end = rowptr[d + 1];
    float a0 = 0, a1 = 0, a2 = 0;
    for (int i = beg + lane; i < end; i += 64) {
        unsigned p = sorted[i];
        unsigned s = p & 0x1FFFFu;
        float4 ha = h1p[2 * s], hb = h1p[2 * s + 1];
        unsigned rel2 = ((p >> 17) & 127u) * 2u;
        float4 wa = w4[rel2], wb = w4[rel2 + 1];
        a0 += ha.x * wa.x + ha.y * wa.y;
        a1 += ha.z * wa.z + ha.w * wa.w;
        a2 += hb.x * wb.x + hb.y * wb.y;
    }
#pragma unroll
    for (int off = 32; off > 0; off >>= 1) {
        a0 += __shfl_down(a0, off); a1 += __shfl_down(a1, off); a2 += __shfl_down(a2, off);
    }
    if (lane == 0) {
        float4 ha = h1p[2 * d], hb = h1p[2 * d + 1];
        float hv[6] = {ha.x, ha.y, ha.z, ha.w, hb.x, hb.y};
        float o[3] = {a0, a1, a2};
#pragma unroll
        for (int j = 0; j < 3; j++) {
            float v = o[j] + bias[j];
#pragma unroll
            for (int k = 0; k < 6; k++) v += hv[k] * root[k * 3 + j];
            o[j] = frelu(v);
        }
        h2p[d] = make_float4(o[0], o[1], o[2], 0.0f);
    }
}

// ---------- L3: wave per dst, mean via cnt16, fused node + pool partials ----------
__launch_bounds__(256)
__global__ void l3_g(const int* __restrict__ rowptr, const unsigned* __restrict__ sorted,
                     const unsigned short* __restrict__ cntA, const float4* __restrict__ h2p,
                     const float* __restrict__ W, const float* __restrict__ root,
                     const float* __restrict__ bias, const int* __restrict__ batch,
                     float* __restrict__ partials, int N) {
    __shared__ float4 w4[NREL * 2];
    __shared__ float redsm[4][8];
    for (int i = threadIdx.x; i < NREL * 2; i += 256) {
        int r = i >> 1;
        w4[i] = (i & 1) ? make_float4(W[r * 6 + 4], W[r * 6 + 5], 0.f, 0.f)
                        : make_float4(W[r * 6], W[r * 6 + 1], W[r * 6 + 2], W[r * 6 + 3]);
    }
    __syncthreads();
    int wv = threadIdx.x >> 6, lane = threadIdx.x & 63;
    int d = blockIdx.x * 4 + wv;
    float a0 = 0, a1 = 0, a2 = 0, a3 = 0, a4 = 0, a5 = 0;
    if (d < N) {
        int beg = rowptr[d], end = rowptr[d + 1];
        for (int i = beg + lane; i < end; i += 64) {
            unsigned p = sorted[i];
            float r = __builtin_amdgcn_rcpf((float)cntA[i]);
            float4 xv = h2p[p & 0x1FFFFu];
            unsigned rel2 = ((p >> 17) & 127u) * 2u;
            float4 wa = w4[rel2], wb = w4[rel2 + 1];
            float x0 = xv.x * r, x1 = xv.y * r, x2 = xv.z * r;
            a0 += x0 * wa.x; a1 += x0 * wa.y;
            a2 += x1 * wa.z; a3 += x1 * wa.w;
            a4 += x2 * wb.x; a5 += x2 * wb.y;
        }
    }
#pragma unroll
    for (int off = 32; off > 0; off >>= 1) {
        a0 += __shfl_down(a0, off); a1 += __shfl_down(a1, off); a2 += __shfl_down(a2, off);
        a3 += __shfl_down(a3, off); a4 += __shfl_down(a4, off); a5 += __shfl_down(a5, off);
    }
    if (lane == 0) {
        float v[7] = {0, 0, 0, 0, 0, 0, 0};
        if (d < N && batch[d] == 0) {
            float4 xv = h2p[d];
            float o[6] = {a0, a1, a2, a3, a4, a5};
#pragma unroll
            for (int j = 0; j < 6; j++)
                v[j] = frelu(o[j] + xv.x * root[j] + xv.y * root[6 + j] +
                             xv.z * root[12 + j] + bias[j]);
            v[6] = 1.0f;
        }
#pragma unroll
        for (int k = 0; k < 7; k++) redsm[wv][k] = v[k];
    }
    __syncthreads();
    if (threadIdx.x == 0) {
#pragma unroll
        for (int k = 0; k < 7; k++)
            partials[(size_t)blockIdx.x * 8 + k] =
                redsm[0][k] + redsm[1][k] + redsm[2][k] + redsm[3][k];
    }
}

// ---------- finalize ----------
__global__ void pool_finalize(const float* __restrict__ partials, int nb,
                              float* __restrict__ out) {
    float v[7] = {0, 0, 0, 0, 0, 0, 0};
    for (int b = threadIdx.x; b < nb; b += blockDim.x) {
#pragma unroll
        for (int k = 0; k < 7; k++) v[k] += partials[(size_t)b * 8 + k];
    }
#pragma unroll
    for (int off = 32; off > 0; off >>= 1) {
#pragma unroll
        for (int k = 0; k < 7; k++) v[k] += __shfl_down(v[k], off);
    }
    __shared__ float sm[16][8];
    int wv = threadIdx.x >> 6, lane = threadIdx.x & 63;
    if (lane == 0) {
#pragma unroll
        for (int k = 0; k < 7; k++) sm[wv][k] = v[k];
    }
    __syncthreads();
    if (threadIdx.x == 0) {
        float t[7] = {0, 0, 0, 0, 0, 0, 0};
        int nw = blockDim.x >> 6;
        for (int q = 0; q < nw; q++) {
#pragma unroll
            for (int k = 0; k < 7; k++) t[k] += sm[q][k];
        }
        float c = t[6] < 1.0f ? 1.0f : t[6];
        float p[6], m = -1e30f;
#pragma unroll
        for (int j = 0; j < 6; j++) { p[j] = t[j] / c; m = fmaxf(m, p[j]); }
        float s = 0.0f;
#pragma unroll
        for (int j = 0; j < 6; j++) s += expf(p[j] - m);
        float lse = m + logf(s);
#pragma unroll
        for (int j = 0; j < 6; j++) out[j] = p[j] - lse;
    }
}

extern "C" void kernel_launch(void* const* d_in, const int* in_sizes, int n_in,
                              void* d_out, int out_size, void* d_ws, size_t ws_size,
                              hipStream_t stream) {
    const float* x     = (const float*)d_in[0];
    const int*   ei    = (const int*)d_in[1];
    const int*   batch = (const int*)d_in[2];
    const int*   etype = (const int*)d_in[3];
    const float* W1    = (const float*)d_in[4];
    const float* root1 = (const float*)d_in[5];
    const float* b1    = (const float*)d_in[6];
    const float* W2    = (const float*)d_in[7];
    const float* root2 = (const float*)d_in[8];
    const float* b2    = (const float*)d_in[9];
    const float* W3    = (const float*)d_in[10];
    const float* root3 = (const float*)d_in[11];
    const float* b3    = (const float*)d_in[12];

    const int N = in_sizes[0] / 3;
    const int E = in_sizes[1] / 2;
    const int* src = ei;
    const int* dst = ei + E;

    char* ws = (char*)d_ws;
    size_t off = 0;
    auto alloc = [&](size_t bytes) -> void* {
        void* p = ws + off;
        off += (bytes + 255) & ~(size_t)255;
        return p;
    };
    int*            bhist   = (int*)           alloc(NBINS * sizeof(int));   // zeroed
    size_t zero_bytes = off;
    int*            bbase   = (int*)           alloc((NBINS + 1) * sizeof(int));
    int*            gcursor = (int*)           alloc(NBINS * sizeof(int));
    unsigned*       edges   = (unsigned*)      alloc((size_t)E * sizeof(unsigned));       // 25.6 MB
    unsigned short* cntA    = (unsigned short*)alloc((size_t)E * sizeof(unsigned short)); // 12.8 MB
    int*            rowptr  = (int*)           alloc((size_t)(N + 1) * sizeof(int));
    float4*         x4      = (float4*)        alloc((size_t)N * sizeof(float4));
    float4*         h1p     = (float4*)        alloc((size_t)N * 2 * sizeof(float4));
    float4*         h2p    = (float4*)         alloc((size_t)N * sizeof(float4));
    const int NBUCK = (N + BNODES - 1) >> BSH;                                            // 782
    const int gW    = (N + 3) / 4;                                                        // 25000
    float*          partials = (float*)        alloc((size_t)gW * 8 * sizeof(float));
    // total ~46 MB

    hipMemsetAsync(d_ws, 0, zero_bytes, stream);

    const int gN = (N + 255) / 256;
    const int gH = (E + HCH - 1) / HCH;
    const int gG = (E + GCH - 1) / GCH;

    padx_k<<<gN, 256, 0, stream>>>(x, x4, N);
    bucket_hist_k<<<gH, 512, 0, stream>>>(dst, bhist, E);
    bucket_scan_k<<<1, 64, 0, stream>>>(bhist, bbase, gcursor);
    group_k<<<gG, 512, 0, stream>>>(src, dst, etype, gcursor, edges, E);
    sortb_k<<<NBUCK, 512, 0, stream>>>(bbase, edges, cntA, rowptr, N);

    l1_g<<<gW, 256, 0, stream>>>(rowptr, edges, cntA, x4, W1, root1, b1, h1p, N);
    l2_g<<<gW, 256, 0, stream>>>(rowptr, edges, h1p, W2, root2, b2, h2p, N);
    l3_g<<<gW, 256, 0, stream>>>(rowptr, edges, cntA, h2p, W3, root3, b3, batch, partials, N);
    pool_finalize<<<1, 1024, 0, stream>>>(partials, gW, (float*)d_out);
}